// Round 9
// baseline (383.183 us; speedup 1.0000x reference)
//
#include <hip/hip_runtime.h>
#include <hip/hip_bf16.h>
#include <stdint.h>

typedef __bf16 bf16;
typedef bf16 bf16x8 __attribute__((ext_vector_type(8)));
typedef float f32x4 __attribute__((ext_vector_type(4)));

// Load 8 consecutive elements as a bf16x8 MFMA operand pack.
__device__ __forceinline__ bf16x8 load8(const float* p) {
    const f32x4 lo = *(const f32x4*)p;
    const f32x4 hi = *(const f32x4*)(p + 4);
    bf16x8 v;
#pragma unroll
    for (int r = 0; r < 4; ++r) { v[r] = (bf16)lo[r]; v[4 + r] = (bf16)hi[r]; }
    return v;
}
__device__ __forceinline__ bf16x8 load8(const bf16* p) {
    return *(const bf16x8*)p;
}

// Direct HBM->LDS 16B async copy (no VGPR round trip). LDS dest is
// wave-uniform base + lane*16B; global src is per-lane.
__device__ __forceinline__ void gload16(const bf16* g, bf16* l) {
    __builtin_amdgcn_global_load_lds((const __attribute__((address_space(1))) void*)g,
                                     (__attribute__((address_space(3))) void*)l, 16, 0, 0);
}

// ---------------------------------------------------------------------------
// fp32 -> bf16 bulk convert (RTN (bf16) cast == what load8(float) did inside
// the old GEMM -> numerically identical).
// ---------------------------------------------------------------------------
__global__ __launch_bounds__(256) void cvt_bf16(const float* __restrict__ src,
                                                bf16* __restrict__ dst, int n8) {
    int idx = blockIdx.x * 256 + threadIdx.x;
    const int stride = gridDim.x * 256;
    for (; idx < n8; idx += stride) {
        const f32x4 lo = *(const f32x4*)(src + (size_t)idx * 8);
        const f32x4 hi = *(const f32x4*)(src + (size_t)idx * 8 + 4);
        bf16x8 v;
#pragma unroll
        for (int r = 0; r < 4; ++r) { v[r] = (bf16)lo[r]; v[4 + r] = (bf16)hi[r]; }
        *(bf16x8*)(dst + (size_t)idx * 8) = v;
    }
}

// Fused convert of x, q_proj, k_proj, v_proj into the contiguous Xb|Wqkv
// region (one launch instead of four).
__global__ __launch_bounds__(256) void cvt_qkvx(const float* __restrict__ x,
                                                const float* __restrict__ q,
                                                const float* __restrict__ k,
                                                const float* __restrict__ v,
                                                bf16* __restrict__ dst,
                                                int nx8, int nq8, int nk8, int nv8) {
    const int total = nx8 + nq8 + nk8 + nv8;
    int idx = blockIdx.x * 256 + threadIdx.x;
    const int stride = gridDim.x * 256;
    for (; idx < total; idx += stride) {
        const float* s;
        int off;
        if (idx < nx8)                   { s = x; off = idx; }
        else if (idx < nx8 + nq8)        { s = q; off = idx - nx8; }
        else if (idx < nx8 + nq8 + nk8)  { s = k; off = idx - nx8 - nq8; }
        else                             { s = v; off = idx - nx8 - nq8 - nk8; }
        const f32x4 lo = *(const f32x4*)(s + (size_t)off * 8);
        const f32x4 hi = *(const f32x4*)(s + (size_t)off * 8 + 4);
        bf16x8 o;
#pragma unroll
        for (int r = 0; r < 4; ++r) { o[r] = (bf16)lo[r]; o[4 + r] = (bf16)hi[r]; }
        *(bf16x8*)(dst + (size_t)idx * 8) = o;
    }
}

// ---------------------------------------------------------------------------
// OLD fp32-operand GEMM (small-workspace fallback path only).
// ---------------------------------------------------------------------------
template <typename AT, typename BT, typename CT>
__global__ __launch_bounds__(256) void gemm_bt(const AT* __restrict__ A,
                                               const BT* __restrict__ B,
                                               CT* __restrict__ C,
                                               int M, int N, int K) {
    __shared__ __align__(16) bf16 As[128 * 32];
    __shared__ __align__(16) bf16 Bs[128 * 32];
    const int tid  = threadIdx.x;
    const int wave = tid >> 6, lane = tid & 63;
    const int quad = lane >> 4, l16 = lane & 15;
    const int m0 = blockIdx.y * 128, n0 = blockIdx.x * 128;
    const int wr = (wave >> 1) * 64, wc = (wave & 1) * 64;

    const int srow = wave * 32 + (lane >> 2);
    const int scol = (lane & 3) * 8;
    const AT* Ag = A + (size_t)(m0 + srow) * K + scol;
    const BT* Bg = B + (size_t)(n0 + srow) * K + scol;
    bf16* Asw = &As[srow * 32 + scol];
    bf16* Bsw = &Bs[srow * 32 + scol];

    f32x4 acc[4][4] = {};

    for (int k0 = 0; k0 < K; k0 += 32) {
        const bf16x8 av0 = load8(Ag + k0);
        const bf16x8 av1 = load8(Ag + k0 + (size_t)16 * K);
        const bf16x8 bv0 = load8(Bg + k0);
        const bf16x8 bv1 = load8(Bg + k0 + (size_t)16 * K);
        __syncthreads();
        *(bf16x8*)(Asw)           = av0;
        *(bf16x8*)(Asw + 16 * 32) = av1;
        *(bf16x8*)(Bsw)           = bv0;
        *(bf16x8*)(Bsw + 16 * 32) = bv1;
        __syncthreads();

        bf16x8 a[4], b[4];
#pragma unroll
        for (int i = 0; i < 4; ++i)
            a[i] = *(const bf16x8*)&As[(wr + i * 16 + l16) * 32 + quad * 8];
#pragma unroll
        for (int j = 0; j < 4; ++j)
            b[j] = *(const bf16x8*)&Bs[(wc + j * 16 + l16) * 32 + quad * 8];
#pragma unroll
        for (int i = 0; i < 4; ++i)
#pragma unroll
            for (int j = 0; j < 4; ++j)
                acc[i][j] = __builtin_amdgcn_mfma_f32_16x16x32_bf16(a[i], b[j], acc[i][j], 0, 0, 0);
    }

#pragma unroll
    for (int i = 0; i < 4; ++i)
#pragma unroll
        for (int j = 0; j < 4; ++j) {
            const int row = m0 + wr + i * 16 + quad * 4;
            const int col = n0 + wc + j * 16 + l16;
#pragma unroll
            for (int r = 0; r < 4; ++r)
                C[(size_t)(row + r) * N + col] = (CT)acc[i][j][r];
        }
}

// ---------------------------------------------------------------------------
// bf16 x bf16 GEMM core with global_load_lds staging (m97 ladder structure).
// C[M,N] = A[M,K] @ B[N,K]^T.
// ---------------------------------------------------------------------------
template <typename CT>
__global__ __launch_bounds__(256) void gemm_bb(const bf16* __restrict__ A,
                                               const bf16* __restrict__ B,
                                               CT* __restrict__ C,
                                               int M, int N, int K) {
    __shared__ __align__(16) bf16 As[128 * 32];
    __shared__ __align__(16) bf16 Bs[128 * 32];
    const int tid  = threadIdx.x;
    const int wave = tid >> 6, lane = tid & 63;
    const int quad = lane >> 4, l16 = lane & 15;
    const int m0 = blockIdx.y * 128, n0 = blockIdx.x * 128;
    const int wr = (wave >> 1) * 64, wc = (wave & 1) * 64;

    const int srow = tid >> 2, scol = (tid & 3) * 8;
    const bf16* Ag = A + (size_t)(m0 + srow) * K + scol;
    const bf16* Bg = B + (size_t)(n0 + srow) * K + scol;
    bf16* Adst = As + wave * 512;   // wave-uniform; HW adds lane*16B
    bf16* Bdst = Bs + wave * 512;

    f32x4 acc[4][4] = {};

    for (int k0 = 0; k0 < K; k0 += 32) {
        __syncthreads();  // readers done with LDS
        gload16(Ag + k0, Adst);
        gload16(Ag + k0 + (size_t)64 * K, Adst + 2048);
        gload16(Bg + k0, Bdst);
        gload16(Bg + k0 + (size_t)64 * K, Bdst + 2048);
        __syncthreads();  // vmcnt(0) drained -> tile visible

        bf16x8 a[4], b[4];
#pragma unroll
        for (int i = 0; i < 4; ++i)
            a[i] = *(const bf16x8*)&As[(wr + i * 16 + l16) * 32 + quad * 8];
#pragma unroll
        for (int j = 0; j < 4; ++j)
            b[j] = *(const bf16x8*)&Bs[(wc + j * 16 + l16) * 32 + quad * 8];
#pragma unroll
        for (int i = 0; i < 4; ++i)
#pragma unroll
            for (int j = 0; j < 4; ++j)
                acc[i][j] = __builtin_amdgcn_mfma_f32_16x16x32_bf16(a[i], b[j], acc[i][j], 0, 0, 0);
    }

#pragma unroll
    for (int i = 0; i < 4; ++i)
#pragma unroll
        for (int j = 0; j < 4; ++j) {
            const int row = m0 + wr + i * 16 + quad * 4;
            const int col = n0 + wc + j * 16 + l16;
#pragma unroll
            for (int r = 0; r < 4; ++r)
                C[(size_t)(row + r) * N + col] = (CT)acc[i][j][r];
        }
}

// ---------------------------------------------------------------------------
// Fused QKV projection: A=Xb [M,2048], W=Wqkv [2560,2048] bf16.
// Epilogue routes per-block (n0 block-uniform): [0,2048)->Q, [2048,2304)->K,
// rest->V.
// ---------------------------------------------------------------------------
__global__ __launch_bounds__(256) void gemm_qkv(const bf16* __restrict__ A,
                                                const bf16* __restrict__ W,
                                                bf16* __restrict__ Cq,
                                                bf16* __restrict__ Ck,
                                                bf16* __restrict__ Cv,
                                                int M, int K) {
    __shared__ __align__(16) bf16 As[128 * 32];
    __shared__ __align__(16) bf16 Bs[128 * 32];
    const int tid  = threadIdx.x;
    const int wave = tid >> 6, lane = tid & 63;
    const int quad = lane >> 4, l16 = lane & 15;
    const int m0 = blockIdx.y * 128, n0 = blockIdx.x * 128;
    const int wr = (wave >> 1) * 64, wc = (wave & 1) * 64;

    const int srow = tid >> 2, scol = (tid & 3) * 8;
    const bf16* Ag = A + (size_t)(m0 + srow) * K + scol;
    const bf16* Bg = W + (size_t)(n0 + srow) * K + scol;
    bf16* Adst = As + wave * 512;
    bf16* Bdst = Bs + wave * 512;

    f32x4 acc[4][4] = {};

    for (int k0 = 0; k0 < K; k0 += 32) {
        __syncthreads();
        gload16(Ag + k0, Adst);
        gload16(Ag + k0 + (size_t)64 * K, Adst + 2048);
        gload16(Bg + k0, Bdst);
        gload16(Bg + k0 + (size_t)64 * K, Bdst + 2048);
        __syncthreads();

        bf16x8 a[4], b[4];
#pragma unroll
        for (int i = 0; i < 4; ++i)
            a[i] = *(const bf16x8*)&As[(wr + i * 16 + l16) * 32 + quad * 8];
#pragma unroll
        for (int j = 0; j < 4; ++j)
            b[j] = *(const bf16x8*)&Bs[(wc + j * 16 + l16) * 32 + quad * 8];
#pragma unroll
        for (int i = 0; i < 4; ++i)
#pragma unroll
            for (int j = 0; j < 4; ++j)
                acc[i][j] = __builtin_amdgcn_mfma_f32_16x16x32_bf16(a[i], b[j], acc[i][j], 0, 0, 0);
    }

    bf16* cb; int cw, coff;
    if (n0 < 2048)      { cb = Cq; cw = 2048; coff = 0; }
    else if (n0 < 2304) { cb = Ck; cw = 256;  coff = 2048; }
    else                { cb = Cv; cw = 256;  coff = 2304; }

#pragma unroll
    for (int i = 0; i < 4; ++i)
#pragma unroll
        for (int j = 0; j < 4; ++j) {
            const int row = m0 + wr + i * 16 + quad * 4;
            const int col = n0 + wc + j * 16 + l16 - coff;
#pragma unroll
            for (int r = 0; r < 4; ++r)
                cb[(size_t)(row + r) * cw + col] = (bf16)acc[i][j][r];
        }
}

// ---------------------------------------------------------------------------
// RMSNorm + RoPE (theta=1e6, half=128), in place on bf16; fp32 weights.
// ---------------------------------------------------------------------------
__device__ __forceinline__ void norm_rope_body(bf16* __restrict__ x,
                                               const float* __restrict__ w,
                                               int rid, int L, int div, int t) {
    const size_t base = (size_t)rid * 256;
    const float v = (float)x[base + t];
    float ss = v * v;
#pragma unroll
    for (int off = 32; off >= 1; off >>= 1) ss += __shfl_xor(ss, off);

    __shared__ float wsum[4];
    __shared__ float buf[256];
    const int wave = t >> 6, lane = t & 63;
    if (lane == 0) wsum[wave] = ss;
    __syncthreads();
    const float var = (wsum[0] + wsum[1] + wsum[2] + wsum[3]) * (1.0f / 256.0f);
    const float inv = rsqrtf(var + 1e-6f);
    buf[t] = v * inv * w[t];
    __syncthreads();

    const int pos = (rid / div) % L;
    const int i = t & 127;
    const float freq = (float)pos * exp2f(-(float)i * (19.93156857f / 128.0f));
    const float c = cosf(freq), s = sinf(freq);
    const float x1 = buf[i], x2 = buf[i + 128];
    const float out = (t < 128) ? (x1 * c - x2 * s) : (x1 * s + x2 * c);
    x[base + t] = (bf16)out;
}

__global__ __launch_bounds__(256) void norm_rope(bf16* __restrict__ x,
                                                 const float* __restrict__ w,
                                                 int L, int div) {
    norm_rope_body(x, w, blockIdx.x, L, div, threadIdx.x);
}

__global__ __launch_bounds__(256) void norm_rope2(bf16* __restrict__ Q,
                                                  bf16* __restrict__ K,
                                                  const float* __restrict__ qw,
                                                  const float* __restrict__ kw,
                                                  int L, int MH) {
    const int row = blockIdx.x;
    if (row < MH) norm_rope_body(Q, qw, row, L, 8, threadIdx.x);
    else          norm_rope_body(K, kw, row - MH, L, 1, threadIdx.x);
}

// ---------------------------------------------------------------------------
// Vt[b][d][l] = V[b][l][d]
// ---------------------------------------------------------------------------
__global__ __launch_bounds__(256) void transpose_v(const bf16* __restrict__ V,
                                                   bf16* __restrict__ Vt, int L) {
    __shared__ bf16 tile[32][33];
    const int b = blockIdx.z;
    const int l0 = blockIdx.x * 32, d0 = blockIdx.y * 32;
    const int tx = threadIdx.x & 31, ty = threadIdx.x >> 5;
#pragma unroll
    for (int i = 0; i < 32; i += 8)
        tile[ty + i][tx] = V[((size_t)b * L + l0 + ty + i) * 256 + d0 + tx];
    __syncthreads();
#pragma unroll
    for (int i = 0; i < 32; i += 8)
        Vt[((size_t)b * 256 + d0 + ty + i) * L + l0 + tx] = tile[tx][ty + i];
}

// XOR-swizzled LDS element indices (col ^= (row&7)<<3 for bf16; 16B granular).
__device__ __forceinline__ int kswz(int r, int c) { return r * 256 + (c ^ ((r & 7) << 3)); }
__device__ __forceinline__ int vswz(int r, int c) { return r * 64  + (c ^ ((r & 7) << 3)); }

// ---------------------------------------------------------------------------
// Causal MQA flash attention, v10 (2 q-subtiles/wave -> half the LDS reads).
// v9 post-mortem: kernel is LDS-port-bound (~82 LDS instrs/wave/step ~= 47us
// of port serialization per CU; staging reorder was null because loads were
// L2-hits already hidden by the partner block). v10 halves LDS reads per
// FLOP: each wave owns 32 q-rows as TWO 16-row subtiles, so every K-frag and
// V-frag ds_read_b128 feeds TWO MFMAs. Same verified 16x16x32 layouts.
// - Block = 128 q-rows (4 waves x 32), KV tile 64. Pair z handles q-tiles
//   {15-z, z} (128-row units); split-KV halves of qt+1 steps each -> every
//   block exactly 17 KV steps. Grid 256 = 1 block/CU.
// - ~300 VGPRs -> __launch_bounds__(256,1): 1 wave/SIMD, 512-reg budget
//   (occupancy can't help a port-bound kernel; registers can).
// - LDS 81,920 B: Ks[64][256] + Vs[256][64] + P 4x2x[16][64], XOR-swizzled;
//   staged via global_load_lds with pre-swizzled source (v8 recipe).
// - v9 split staging kept: K(t+1) under softmax+PV, V(t+1) under QK^T(t+1).
// SPLIT=1 writes f32 partials + (m,l) (absolute-row layout); merge combines.
// ---------------------------------------------------------------------------
template <int SPLIT>
__global__ __launch_bounds__(256, 1) void flash_attn(const bf16* __restrict__ Q,
                                                     const bf16* __restrict__ K,
                                                     const bf16* __restrict__ Vt,
                                                     bf16* __restrict__ Ctx,
                                                     float* __restrict__ P0,
                                                     float* __restrict__ P1,
                                                     float* __restrict__ ML0,
                                                     float* __restrict__ ML1, int L) {
    constexpr int H = 8, HD = 256;
    extern __shared__ __align__(16) bf16 smem[];
    bf16* Ks = smem;                    // [64][256] swizzled
    bf16* Vs = Ks + 64 * 256;           // [256][64] swizzled
    bf16* Ps = Vs + 256 * 64;           // 4 waves x 2 subtiles x [16][64] swz

    const int z = blockIdx.x, h = blockIdx.y;
    const int b    = SPLIT ? ((int)blockIdx.z >> 1) : (int)blockIdx.z;
    const int half = SPLIT ? ((int)blockIdx.z & 1) : 0;
    const int tid = threadIdx.x;
    const int wave = tid >> 6, lane = tid & 63;
    const int quad = lane >> 4, l16 = lane & 15;
    const int nQT = L / 128;            // 128-row q-tiles

    const bf16* Kb = K + (size_t)b * L * HD;
    const bf16* Vb = Vt + (size_t)b * HD * L;
    bf16* Pw = Ps + wave * 2048;        // 2 x [16][64]

    // cooperative staging maps; LDS dest linear (elem = tid*8), global source
    // column pre-swizzled (involution; row&7 invariant across rounds).
    const int krow = tid >> 5, kcol = (tid & 31) * 8;
    const int vrow = tid >> 3, vcol = (tid & 7) * 8;
    const int kcs = kcol ^ ((krow & 7) << 3);
    const int vcs = vcol ^ ((vrow & 7) << 3);
    bf16* kdst = Ks + wave * 512;       // + i*2048 per round; wave-uniform
    bf16* vdst = Vs + wave * 512;

    for (int pass = 0; pass < 2; ++pass) {
        const int qt  = pass ? z : (nQT - 1 - z);
        const int qb0 = qt * 128 + wave * 32;     // wave's first q row
        const int s   = 2 * (qt + 1);             // KV tiles for this q-tile
        const int c0  = qt + 1;                   // half split (s even)
        const int kt0 = (SPLIT && half) ? c0 : 0;
        const int cnt = SPLIT ? c0 : s;

        // Q fragments, 2 subtiles: A[m=l16][k=quad*8+j], k-chunks of 32
        bf16x8 qf[2][8];
#pragma unroll
        for (int sub = 0; sub < 2; ++sub) {
            const bf16* qbase = Q + ((size_t)(b * L + qb0 + sub * 16 + l16) * H + h) * HD + quad * 8;
#pragma unroll
            for (int kc = 0; kc < 8; ++kc) qf[sub][kc] = *(const bf16x8*)(qbase + kc * 32);
        }

        f32x4 Oacc[2][16] = {};
        float mrow[2][4], lrow[2][4];
#pragma unroll
        for (int sub = 0; sub < 2; ++sub)
#pragma unroll
            for (int r = 0; r < 4; ++r) { mrow[sub][r] = -1e30f; lrow[sub][r] = 0.0f; }

        __syncthreads();  // B0: prev pass's LDS readers done -> reuse safe
        {                 // stage tile kt0
            const int kv0 = kt0 * 64;
#pragma unroll
            for (int i = 0; i < 8; ++i)
                gload16(Kb + (size_t)(kv0 + i * 8 + krow) * HD + kcs, kdst + i * 2048);
#pragma unroll
            for (int i = 0; i < 8; ++i)
                gload16(Vb + (size_t)(i * 32 + vrow) * L + kv0 + vcs, vdst + i * 2048);
        }
        __syncthreads();  // B1: vmcnt(0) drained -> tile 0 visible

        for (int it = 0; it < cnt; ++it) {
            const int kt = kt0 + it;
            const int kv0 = kt * 64;
            const int nv0 = kv0 + 64;
            const bool more = (it + 1 < cnt);

            // ---- S = Q K^T: each K-frag read feeds both subtiles ----
            f32x4 S[2][4];
#pragma unroll
            for (int nt = 0; nt < 4; ++nt) {
                f32x4 s0 = {0.f, 0.f, 0.f, 0.f}, s1 = {0.f, 0.f, 0.f, 0.f};
                const int krw = nt * 16 + l16;
#pragma unroll
                for (int kc = 0; kc < 8; ++kc) {
                    const bf16x8 kf = *(const bf16x8*)&Ks[kswz(krw, quad * 8 + kc * 32)];
                    s0 = __builtin_amdgcn_mfma_f32_16x16x32_bf16(qf[0][kc], kf, s0, 0, 0, 0);
                    s1 = __builtin_amdgcn_mfma_f32_16x16x32_bf16(qf[1][kc], kf, s1, 0, 0, 0);
                }
                S[0][nt] = s0; S[1][nt] = s1;
            }

            __syncthreads();  // Ks readers done (drains prior V loads, overlapped)
            if (more) {       // stage K(t+1): hidden under softmax+PV below
#pragma unroll
                for (int i = 0; i < 8; ++i)
                    gload16(Kb + (size_t)(nv0 + i * 8 + krow) * HD + kcs, kdst + i * 2048);
            }

            // ---- scale + causal mask + row max (per subtile) ----
            float rowmax[2][4];
#pragma unroll
            for (int sub = 0; sub < 2; ++sub) {
                const int q0s = qb0 + sub * 16;
                const bool dm = (kv0 + 63 > q0s);
#pragma unroll
                for (int r = 0; r < 4; ++r) rowmax[sub][r] = -1e30f;
#pragma unroll
                for (int nt = 0; nt < 4; ++nt) {
                    const int col = kv0 + nt * 16 + l16;
#pragma unroll
                    for (int r = 0; r < 4; ++r) {
                        float sv = S[sub][nt][r] * 0.0625f;  // 1/sqrt(256)
                        if (dm && col > q0s + quad * 4 + r) sv = -1e30f;
                        S[sub][nt][r] = sv;
                        rowmax[sub][r] = fmaxf(rowmax[sub][r], sv);
                    }
                }
            }
#pragma unroll
            for (int off = 1; off < 16; off <<= 1)
#pragma unroll
                for (int sub = 0; sub < 2; ++sub)
#pragma unroll
                    for (int r = 0; r < 4; ++r)
                        rowmax[sub][r] = fmaxf(rowmax[sub][r], __shfl_xor(rowmax[sub][r], off));

            // ---- online softmax (per subtile) ----
            float alpha[2][4], rsum[2][4];
#pragma unroll
            for (int sub = 0; sub < 2; ++sub)
#pragma unroll
                for (int r = 0; r < 4; ++r) {
                    const float mnew = fmaxf(mrow[sub][r], rowmax[sub][r]);
                    alpha[sub][r] = __expf(mrow[sub][r] - mnew);
                    mrow[sub][r] = mnew;
                    rsum[sub][r] = 0.0f;
                }
#pragma unroll
            for (int sub = 0; sub < 2; ++sub)
#pragma unroll
                for (int nt = 0; nt < 4; ++nt)
#pragma unroll
                    for (int r = 0; r < 4; ++r) {
                        const float p = __expf(S[sub][nt][r] - mrow[sub][r]);
                        rsum[sub][r] += p;
                        Pw[sub * 1024 + vswz(quad * 4 + r, nt * 16 + l16)] = (bf16)p;
                    }
#pragma unroll
            for (int off = 1; off < 16; off <<= 1)
#pragma unroll
                for (int sub = 0; sub < 2; ++sub)
#pragma unroll
                    for (int r = 0; r < 4; ++r) rsum[sub][r] += __shfl_xor(rsum[sub][r], off);
#pragma unroll
            for (int sub = 0; sub < 2; ++sub)
#pragma unroll
                for (int r = 0; r < 4; ++r)
                    lrow[sub][r] = lrow[sub][r] * alpha[sub][r] + rsum[sub][r];

            // ---- rescale O, then O += P V: each V-frag feeds both subs ----
#pragma unroll
            for (int sub = 0; sub < 2; ++sub)
#pragma unroll
                for (int nt = 0; nt < 16; ++nt)
#pragma unroll
                    for (int r = 0; r < 4; ++r) Oacc[sub][nt][r] *= alpha[sub][r];

            bf16x8 pf[2][2];
#pragma unroll
            for (int sub = 0; sub < 2; ++sub)
#pragma unroll
                for (int ks = 0; ks < 2; ++ks)
                    pf[sub][ks] = *(const bf16x8*)&Pw[sub * 1024 + vswz(l16, ks * 32 + quad * 8)];
#pragma unroll
            for (int nt = 0; nt < 16; ++nt) {
                const int vrw = nt * 16 + l16;
                f32x4 o0 = Oacc[0][nt], o1 = Oacc[1][nt];
#pragma unroll
                for (int ks = 0; ks < 2; ++ks) {
                    const bf16x8 vf = *(const bf16x8*)&Vs[vswz(vrw, ks * 32 + quad * 8)];
                    o0 = __builtin_amdgcn_mfma_f32_16x16x32_bf16(pf[0][ks], vf, o0, 0, 0, 0);
                    o1 = __builtin_amdgcn_mfma_f32_16x16x32_bf16(pf[1][ks], vf, o1, 0, 0, 0);
                }
                Oacc[0][nt] = o0; Oacc[1][nt] = o1;
            }

            __syncthreads();  // Vs/P readers done (drains K(t+1), overlapped)
            if (more) {       // stage V(t+1): hidden under next QK^T
#pragma unroll
                for (int i = 0; i < 8; ++i)
                    gload16(Vb + (size_t)(i * 32 + vrow) * L + nv0 + vcs, vdst + i * 2048);
            }
        }

        if (SPLIT) {
            // ---- epilogue: un-normalized partial O (f32) + (m,l), abs rows ----
            float* Pd  = half ? P1 : P0;
            float* MLd = half ? ML1 : ML0;
#pragma unroll
            for (int sub = 0; sub < 2; ++sub) {
                const size_t rowbase = (size_t)(b * H + h) * L + qb0 + sub * 16;
                float* prow = Pd + rowbase * 256;
#pragma unroll
                for (int nt = 0; nt < 16; ++nt)
#pragma unroll
                    for (int r = 0; r < 4; ++r)
                        prow[(size_t)(quad * 4 + r) * 256 + nt * 16 + l16] = Oacc[sub][nt][r];
                if (l16 == 0) {
#pragma unroll
                    for (int r = 0; r < 4; ++r) {
                        const size_t rr = rowbase + quad * 4 + r;
                        MLd[rr * 2 + 0] = mrow[sub][r];
                        MLd[rr * 2 + 1] = lrow[sub][r];
                    }
                }
            }
        } else {
            // ---- epilogue: /l, store to Ctx (B,L,H*HD) ----
#pragma unroll
            for (int sub = 0; sub < 2; ++sub) {
                bf16* obase = Ctx + ((size_t)(b * L + qb0 + sub * 16) * H + h) * HD;
#pragma unroll
                for (int nt = 0; nt < 16; ++nt)
#pragma unroll
                    for (int r = 0; r < 4; ++r) {
                        const float val = Oacc[sub][nt][r] / lrow[sub][r];
                        obase[(size_t)(quad * 4 + r) * (H * HD) + nt * 16 + l16] = (bf16)val;
                    }
            }
        }
    }
}

// ---------------------------------------------------------------------------
// Ctx merge of the two KV halves (absolute-row partial layout).
// ---------------------------------------------------------------------------
__global__ __launch_bounds__(256) void merge_partials(const float* __restrict__ P0,
                                                      const float* __restrict__ P1,
                                                      const float* __restrict__ ML0,
                                                      const float* __restrict__ ML1,
                                                      bf16* __restrict__ Ctx, int L) {
    constexpr int H = 8, HD = 256;
    const int qt = blockIdx.x, h = blockIdx.y, b = blockIdx.z;
    const int t = threadIdx.x;
    const size_t rowbase = (size_t)(b * H + h) * L + qt * 64;
    const int rlo = t >> 6;
    const int d = (t & 63) * 4;
#pragma unroll
    for (int it = 0; it < 16; ++it) {
        const int r = it * 4 + rlo;
        const size_t rr = rowbase + r;
        const float m0 = ML0[rr * 2], l0 = ML0[rr * 2 + 1];
        const float m1 = ML1[rr * 2], l1 = ML1[rr * 2 + 1];
        const float mn = fmaxf(m0, m1);
        const float a0 = __expf(m0 - mn), a1 = __expf(m1 - mn);
        const float linv = 1.0f / (l0 * a0 + l1 * a1);
        const f32x4 o0 = *(const f32x4*)&P0[rr * 256 + d];
        const f32x4 o1 = *(const f32x4*)&P1[rr * 256 + d];
        bf16* op = Ctx + ((size_t)(b * L + qt * 64 + r) * H + h) * HD + d;
#pragma unroll
        for (int j = 0; j < 4; ++j) op[j] = (bf16)((o0[j] * a0 + o1[j] * a1) * linv);
    }
}

// ---------------------------------------------------------------------------
extern "C" void kernel_launch(void* const* d_in, const int* in_sizes, int n_in,
                              void* d_out, int out_size, void* d_ws, size_t ws_size,
                              hipStream_t stream) {
    const float* x      = (const float*)d_in[0];
    const float* q_proj = (const float*)d_in[1];
    const float* k_proj = (const float*)d_in[2];
    const float* v_proj = (const float*)d_in[3];
    const float* o_proj = (const float*)d_in[4];
    const float* q_norm = (const float*)d_in[5];
    const float* k_norm = (const float*)d_in[6];
    float* out = (float*)d_out;

    constexpr int B = 2, L = 2048, D = 2048, H = 8, HD = 256;
    constexpr int M = B * L;            // 4096
    constexpr int NQKV = D + 2 * HD;    // 2560
    constexpr int FLASH_LDS = (64 * 256 + 256 * 64 + 4 * 2 * 16 * 64) * 2;  // 81,920 B

    static bool attr_set = false;  // host-side once; same device work every call
    if (!attr_set) {
        (void)hipFuncSetAttribute((const void*)flash_attn<0>,
                                  hipFuncAttributeMaxDynamicSharedMemorySize, FLASH_LDS);
        (void)hipFuncSetAttribute((const void*)flash_attn<1>,
                                  hipFuncAttributeMaxDynamicSharedMemorySize, FLASH_LDS);
        attr_set = true;
    }

    bf16* Qw  = (bf16*)d_ws;                 // M * D      (B,L,H,HD)
    bf16* Kw  = Qw  + (size_t)M * D;         // M * HD     (B,L,HD)
    bf16* Vw  = Kw  + (size_t)M * HD;        // M * HD
    bf16* Vtw = Vw  + (size_t)M * HD;        // B * HD * L
    bf16* Ctx = Vtw + (size_t)M * HD;        // M * D

    // Shared region (time-multiplexed, in stream order):
    //   phase 1 (projections): Xb [M*D bf16] + Wqkv [2560*D bf16]
    //   phase 2 (flash):       P0,P1 [f32 partials] + ML0,ML1
    //   phase 3 (o-proj):      Ob [D*D bf16] aliases region start
    char* region = (char*)(Ctx + (size_t)M * D);
    bf16* Xb   = (bf16*)region;
    bf16* Wqkv = Xb + (size_t)M * D;
    constexpr size_t PELEMS  = (size_t)B * H * L * 256;  // 8,388,608
    constexpr size_t MLELEMS = (size_t)B * H * L * 2;    // 65,536
    float* P0  = (float*)region;
    float* P1  = P0 + PELEMS;
    float* ML0 = P1 + PELEMS;
    float* ML1 = ML0 + MLELEMS;
    bf16*  Ob  = (bf16*)region;
    const size_t ws_needed = (size_t)((char*)(ML1 + MLELEMS) - (char*)d_ws);

    if (ws_size >= ws_needed) {
        // ---- fast path ----
        cvt_qkvx<<<2048, 256, 0, stream>>>(x, q_proj, k_proj, v_proj, Xb,
                                           M * D / 8, D * D / 8, HD * D / 8, HD * D / 8);
        gemm_qkv<<<dim3(NQKV / 128, M / 128), 256, 0, stream>>>(Xb, Wqkv, Qw, Kw, Vw, M, D);
        norm_rope2<<<M * H + M, 256, 0, stream>>>(Qw, Kw, q_norm, k_norm, L, M * H);
        transpose_v<<<dim3(L / 32, HD / 32, B), 256, 0, stream>>>(Vw, Vtw, L);
        flash_attn<1><<<dim3(L / 256, H, B * 2), 256, FLASH_LDS, stream>>>(Qw, Kw, Vtw, Ctx,
                                                                           P0, P1, ML0, ML1, L);
        merge_partials<<<dim3(L / 64, H, B), 256, 0, stream>>>(P0, P1, ML0, ML1, Ctx, L);
        cvt_bf16<<<2048, 256, 0, stream>>>(o_proj, Ob, D * D / 8);  // Ob aliases dead P0
        gemm_bb<float><<<dim3(D / 128, M / 128), 256, 0, stream>>>(Ctx, Ob, out, M, D, D);
    } else {
        // ---- fallback: fp32-operand GEMMs, single-pass flash ----
        gemm_bt<float, float, bf16><<<dim3(D / 128, M / 128), 256, 0, stream>>>(x, q_proj, Qw, M, D, D);
        gemm_bt<float, float, bf16><<<dim3(HD / 128, M / 128), 256, 0, stream>>>(x, k_proj, Kw, M, HD, D);
        gemm_bt<float, float, bf16><<<dim3(HD / 128, M / 128), 256, 0, stream>>>(x, v_proj, Vw, M, HD, D);
        norm_rope<<<M * H, 256, 0, stream>>>(Qw, q_norm, L, H);
        norm_rope<<<M, 256, 0, stream>>>(Kw, k_norm, L, 1);
        transpose_v<<<dim3(L / 32, HD / 32, B), 256, 0, stream>>>(Vw, Vtw, L);
        flash_attn<0><<<dim3(L / 256, H, B), 256, FLASH_LDS, stream>>>(Qw, Kw, Vtw, Ctx,
                                                                       P0, P1, ML0, ML1, L);
        gemm_bt<bf16, float, float><<<dim3(D / 128, M / 128), 256, 0, stream>>>(Ctx, o_proj, out, M, D, D);
    }
}

// Round 10
// 375.825 us; speedup vs baseline: 1.0196x; 1.0196x over previous
//
#include <hip/hip_runtime.h>
#include <hip/hip_bf16.h>
#include <stdint.h>

typedef __bf16 bf16;
typedef bf16 bf16x8 __attribute__((ext_vector_type(8)));
typedef float f32x4 __attribute__((ext_vector_type(4)));

// Load 8 consecutive elements as a bf16x8 MFMA operand pack.
__device__ __forceinline__ bf16x8 load8(const float* p) {
    const f32x4 lo = *(const f32x4*)p;
    const f32x4 hi = *(const f32x4*)(p + 4);
    bf16x8 v;
#pragma unroll
    for (int r = 0; r < 4; ++r) { v[r] = (bf16)lo[r]; v[4 + r] = (bf16)hi[r]; }
    return v;
}
__device__ __forceinline__ bf16x8 load8(const bf16* p) {
    return *(const bf16x8*)p;
}

// Direct HBM->LDS 16B async copy (no VGPR round trip). LDS dest is
// wave-uniform base + lane*16B; global src is per-lane.
__device__ __forceinline__ void gload16(const bf16* g, bf16* l) {
    __builtin_amdgcn_global_load_lds((const __attribute__((address_space(1))) void*)g,
                                     (__attribute__((address_space(3))) void*)l, 16, 0, 0);
}

// ---------------------------------------------------------------------------
// fp32 -> bf16 bulk convert (RTN (bf16) cast == what load8(float) did inside
// the old GEMM -> numerically identical).
// ---------------------------------------------------------------------------
__global__ __launch_bounds__(256) void cvt_bf16(const float* __restrict__ src,
                                                bf16* __restrict__ dst, int n8) {
    int idx = blockIdx.x * 256 + threadIdx.x;
    const int stride = gridDim.x * 256;
    for (; idx < n8; idx += stride) {
        const f32x4 lo = *(const f32x4*)(src + (size_t)idx * 8);
        const f32x4 hi = *(const f32x4*)(src + (size_t)idx * 8 + 4);
        bf16x8 v;
#pragma unroll
        for (int r = 0; r < 4; ++r) { v[r] = (bf16)lo[r]; v[4 + r] = (bf16)hi[r]; }
        *(bf16x8*)(dst + (size_t)idx * 8) = v;
    }
}

// Fused convert of x, q_proj, k_proj, v_proj into the contiguous Xb|Wqkv
// region (one launch instead of four).
__global__ __launch_bounds__(256) void cvt_qkvx(const float* __restrict__ x,
                                                const float* __restrict__ q,
                                                const float* __restrict__ k,
                                                const float* __restrict__ v,
                                                bf16* __restrict__ dst,
                                                int nx8, int nq8, int nk8, int nv8) {
    const int total = nx8 + nq8 + nk8 + nv8;
    int idx = blockIdx.x * 256 + threadIdx.x;
    const int stride = gridDim.x * 256;
    for (; idx < total; idx += stride) {
        const float* s;
        int off;
        if (idx < nx8)                   { s = x; off = idx; }
        else if (idx < nx8 + nq8)        { s = q; off = idx - nx8; }
        else if (idx < nx8 + nq8 + nk8)  { s = k; off = idx - nx8 - nq8; }
        else                             { s = v; off = idx - nx8 - nq8 - nk8; }
        const f32x4 lo = *(const f32x4*)(s + (size_t)off * 8);
        const f32x4 hi = *(const f32x4*)(s + (size_t)off * 8 + 4);
        bf16x8 o;
#pragma unroll
        for (int r = 0; r < 4; ++r) { o[r] = (bf16)lo[r]; o[4 + r] = (bf16)hi[r]; }
        *(bf16x8*)(dst + (size_t)idx * 8) = o;
    }
}

// ---------------------------------------------------------------------------
// OLD fp32-operand GEMM (small-workspace fallback path only).
// ---------------------------------------------------------------------------
template <typename AT, typename BT, typename CT>
__global__ __launch_bounds__(256) void gemm_bt(const AT* __restrict__ A,
                                               const BT* __restrict__ B,
                                               CT* __restrict__ C,
                                               int M, int N, int K) {
    __shared__ __align__(16) bf16 As[128 * 32];
    __shared__ __align__(16) bf16 Bs[128 * 32];
    const int tid  = threadIdx.x;
    const int wave = tid >> 6, lane = tid & 63;
    const int quad = lane >> 4, l16 = lane & 15;
    const int m0 = blockIdx.y * 128, n0 = blockIdx.x * 128;
    const int wr = (wave >> 1) * 64, wc = (wave & 1) * 64;

    const int srow = wave * 32 + (lane >> 2);
    const int scol = (lane & 3) * 8;
    const AT* Ag = A + (size_t)(m0 + srow) * K + scol;
    const BT* Bg = B + (size_t)(n0 + srow) * K + scol;
    bf16* Asw = &As[srow * 32 + scol];
    bf16* Bsw = &Bs[srow * 32 + scol];

    f32x4 acc[4][4] = {};

    for (int k0 = 0; k0 < K; k0 += 32) {
        const bf16x8 av0 = load8(Ag + k0);
        const bf16x8 av1 = load8(Ag + k0 + (size_t)16 * K);
        const bf16x8 bv0 = load8(Bg + k0);
        const bf16x8 bv1 = load8(Bg + k0 + (size_t)16 * K);
        __syncthreads();
        *(bf16x8*)(Asw)           = av0;
        *(bf16x8*)(Asw + 16 * 32) = av1;
        *(bf16x8*)(Bsw)           = bv0;
        *(bf16x8*)(Bsw + 16 * 32) = bv1;
        __syncthreads();

        bf16x8 a[4], b[4];
#pragma unroll
        for (int i = 0; i < 4; ++i)
            a[i] = *(const bf16x8*)&As[(wr + i * 16 + l16) * 32 + quad * 8];
#pragma unroll
        for (int j = 0; j < 4; ++j)
            b[j] = *(const bf16x8*)&Bs[(wc + j * 16 + l16) * 32 + quad * 8];
#pragma unroll
        for (int i = 0; i < 4; ++i)
#pragma unroll
            for (int j = 0; j < 4; ++j)
                acc[i][j] = __builtin_amdgcn_mfma_f32_16x16x32_bf16(a[i], b[j], acc[i][j], 0, 0, 0);
    }

#pragma unroll
    for (int i = 0; i < 4; ++i)
#pragma unroll
        for (int j = 0; j < 4; ++j) {
            const int row = m0 + wr + i * 16 + quad * 4;
            const int col = n0 + wc + j * 16 + l16;
#pragma unroll
            for (int r = 0; r < 4; ++r)
                C[(size_t)(row + r) * N + col] = (CT)acc[i][j][r];
        }
}

// ---------------------------------------------------------------------------
// bf16 x bf16 GEMM, 128x64 tile (BM=128, BN=64), BK=32, gload staging.
// v10 GEMM post-mortem: 128x128 tiles gave only 512-640 blocks = 2/CU,
// grid-limited at ~21% occupancy (m102 shape curve). 128x64 doubles the
// grid to 4-5 blocks/CU; LDS 12 KB, ~64 VGPR leave occupancy grid-bound.
// C[M,N] = A[M,K] @ B[N,K]^T. Wave w owns rows (w>>1)*64, cols (w&1)*32.
// ---------------------------------------------------------------------------
template <typename CT>
__global__ __launch_bounds__(256) void gemm_bb(const bf16* __restrict__ A,
                                               const bf16* __restrict__ B,
                                               CT* __restrict__ C,
                                               int M, int N, int K) {
    __shared__ __align__(16) bf16 As[128 * 32];
    __shared__ __align__(16) bf16 Bs[64 * 32];
    const int tid  = threadIdx.x;
    const int wave = tid >> 6, lane = tid & 63;
    const int quad = lane >> 4, l16 = lane & 15;
    const int m0 = blockIdx.y * 128, n0 = blockIdx.x * 64;
    const int wr = (wave >> 1) * 64, wc = (wave & 1) * 32;

    const int srow = tid >> 2, scol = (tid & 3) * 8;   // rows 0..63
    const bf16* Ag = A + (size_t)(m0 + srow) * K + scol;
    const bf16* Bg = B + (size_t)(n0 + srow) * K + scol;
    bf16* Adst = As + wave * 512;   // wave-uniform; HW adds lane*16B
    bf16* Bdst = Bs + wave * 512;

    f32x4 acc[4][2] = {};

    for (int k0 = 0; k0 < K; k0 += 32) {
        __syncthreads();  // readers done with LDS
        gload16(Ag + k0, Adst);
        gload16(Ag + k0 + (size_t)64 * K, Adst + 2048);  // rows 64..127
        gload16(Bg + k0, Bdst);
        __syncthreads();  // vmcnt(0) drained -> tile visible

        bf16x8 a[4], b[2];
#pragma unroll
        for (int i = 0; i < 4; ++i)
            a[i] = *(const bf16x8*)&As[(wr + i * 16 + l16) * 32 + quad * 8];
#pragma unroll
        for (int j = 0; j < 2; ++j)
            b[j] = *(const bf16x8*)&Bs[(wc + j * 16 + l16) * 32 + quad * 8];
#pragma unroll
        for (int i = 0; i < 4; ++i)
#pragma unroll
            for (int j = 0; j < 2; ++j)
                acc[i][j] = __builtin_amdgcn_mfma_f32_16x16x32_bf16(a[i], b[j], acc[i][j], 0, 0, 0);
    }

#pragma unroll
    for (int i = 0; i < 4; ++i)
#pragma unroll
        for (int j = 0; j < 2; ++j) {
            const int row = m0 + wr + i * 16 + quad * 4;
            const int col = n0 + wc + j * 16 + l16;
#pragma unroll
            for (int r = 0; r < 4; ++r)
                C[(size_t)(row + r) * N + col] = (CT)acc[i][j][r];
        }
}

// ---------------------------------------------------------------------------
// Fused QKV projection, 128x64 tile: A=Xb [M,2048], W=Wqkv [2560,2048] bf16.
// Epilogue routes per-block (n0 block-uniform, 64-granular; boundaries 2048
// and 2304 are multiples of 64): [0,2048)->Q, [2048,2304)->K, rest->V.
// ---------------------------------------------------------------------------
__global__ __launch_bounds__(256) void gemm_qkv(const bf16* __restrict__ A,
                                                const bf16* __restrict__ W,
                                                bf16* __restrict__ Cq,
                                                bf16* __restrict__ Ck,
                                                bf16* __restrict__ Cv,
                                                int M, int K) {
    __shared__ __align__(16) bf16 As[128 * 32];
    __shared__ __align__(16) bf16 Bs[64 * 32];
    const int tid  = threadIdx.x;
    const int wave = tid >> 6, lane = tid & 63;
    const int quad = lane >> 4, l16 = lane & 15;
    const int m0 = blockIdx.y * 128, n0 = blockIdx.x * 64;
    const int wr = (wave >> 1) * 64, wc = (wave & 1) * 32;

    const int srow = tid >> 2, scol = (tid & 3) * 8;
    const bf16* Ag = A + (size_t)(m0 + srow) * K + scol;
    const bf16* Bg = W + (size_t)(n0 + srow) * K + scol;
    bf16* Adst = As + wave * 512;
    bf16* Bdst = Bs + wave * 512;

    f32x4 acc[4][2] = {};

    for (int k0 = 0; k0 < K; k0 += 32) {
        __syncthreads();
        gload16(Ag + k0, Adst);
        gload16(Ag + k0 + (size_t)64 * K, Adst + 2048);
        gload16(Bg + k0, Bdst);
        __syncthreads();

        bf16x8 a[4], b[2];
#pragma unroll
        for (int i = 0; i < 4; ++i)
            a[i] = *(const bf16x8*)&As[(wr + i * 16 + l16) * 32 + quad * 8];
#pragma unroll
        for (int j = 0; j < 2; ++j)
            b[j] = *(const bf16x8*)&Bs[(wc + j * 16 + l16) * 32 + quad * 8];
#pragma unroll
        for (int i = 0; i < 4; ++i)
#pragma unroll
            for (int j = 0; j < 2; ++j)
                acc[i][j] = __builtin_amdgcn_mfma_f32_16x16x32_bf16(a[i], b[j], acc[i][j], 0, 0, 0);
    }

    bf16* cb; int cw, coff;
    if (n0 < 2048)      { cb = Cq; cw = 2048; coff = 0; }
    else if (n0 < 2304) { cb = Ck; cw = 256;  coff = 2048; }
    else                { cb = Cv; cw = 256;  coff = 2304; }

#pragma unroll
    for (int i = 0; i < 4; ++i)
#pragma unroll
        for (int j = 0; j < 2; ++j) {
            const int row = m0 + wr + i * 16 + quad * 4;
            const int col = n0 + wc + j * 16 + l16 - coff;
#pragma unroll
            for (int r = 0; r < 4; ++r)
                cb[(size_t)(row + r) * cw + col] = (bf16)acc[i][j][r];
        }
}

// ---------------------------------------------------------------------------
// RMSNorm + RoPE (theta=1e6, half=128), in place on bf16; fp32 weights.
// ---------------------------------------------------------------------------
__device__ __forceinline__ void norm_rope_body(bf16* __restrict__ x,
                                               const float* __restrict__ w,
                                               int rid, int L, int div, int t) {
    const size_t base = (size_t)rid * 256;
    const float v = (float)x[base + t];
    float ss = v * v;
#pragma unroll
    for (int off = 32; off >= 1; off >>= 1) ss += __shfl_xor(ss, off);

    __shared__ float wsum[4];
    __shared__ float buf[256];
    const int wave = t >> 6, lane = t & 63;
    if (lane == 0) wsum[wave] = ss;
    __syncthreads();
    const float var = (wsum[0] + wsum[1] + wsum[2] + wsum[3]) * (1.0f / 256.0f);
    const float inv = rsqrtf(var + 1e-6f);
    buf[t] = v * inv * w[t];
    __syncthreads();

    const int pos = (rid / div) % L;
    const int i = t & 127;
    const float freq = (float)pos * exp2f(-(float)i * (19.93156857f / 128.0f));
    const float c = cosf(freq), s = sinf(freq);
    const float x1 = buf[i], x2 = buf[i + 128];
    const float out = (t < 128) ? (x1 * c - x2 * s) : (x1 * s + x2 * c);
    x[base + t] = (bf16)out;
}

__global__ __launch_bounds__(256) void norm_rope(bf16* __restrict__ x,
                                                 const float* __restrict__ w,
                                                 int L, int div) {
    norm_rope_body(x, w, blockIdx.x, L, div, threadIdx.x);
}

__global__ __launch_bounds__(256) void norm_rope2(bf16* __restrict__ Q,
                                                  bf16* __restrict__ K,
                                                  const float* __restrict__ qw,
                                                  const float* __restrict__ kw,
                                                  int L, int MH) {
    const int row = blockIdx.x;
    if (row < MH) norm_rope_body(Q, qw, row, L, 8, threadIdx.x);
    else          norm_rope_body(K, kw, row - MH, L, 1, threadIdx.x);
}

// ---------------------------------------------------------------------------
// Vt[b][d][l] = V[b][l][d]
// ---------------------------------------------------------------------------
__global__ __launch_bounds__(256) void transpose_v(const bf16* __restrict__ V,
                                                   bf16* __restrict__ Vt, int L) {
    __shared__ bf16 tile[32][33];
    const int b = blockIdx.z;
    const int l0 = blockIdx.x * 32, d0 = blockIdx.y * 32;
    const int tx = threadIdx.x & 31, ty = threadIdx.x >> 5;
#pragma unroll
    for (int i = 0; i < 32; i += 8)
        tile[ty + i][tx] = V[((size_t)b * L + l0 + ty + i) * 256 + d0 + tx];
    __syncthreads();
#pragma unroll
    for (int i = 0; i < 32; i += 8)
        Vt[((size_t)b * 256 + d0 + ty + i) * L + l0 + tx] = tile[tx][ty + i];
}

// XOR-swizzled LDS element indices (col ^= (row&7)<<3 for bf16; 16B granular).
__device__ __forceinline__ int kswz(int r, int c) { return r * 256 + (c ^ ((r & 7) << 3)); }
__device__ __forceinline__ int vswz(int r, int c) { return r * 64  + (c ^ ((r & 7) << 3)); }

// ---------------------------------------------------------------------------
// Causal MQA flash attention, v9 (REVERTED from v10: the 2-subtile variant
// halved LDS reads but needed 244 VGPR -> 1 wave/SIMD -> all dep chains
// exposed, net -38%. v9's 2 blocks/CU co-residency is worth more than
// halved LDS traffic. 80.7us proven).
// Block (z,half) does half the KV range of q-tile pair {nqt-1-z, z}.
// SPLIT=1 writes f32 partials + (m,l); merge_partials combines.
// ---------------------------------------------------------------------------
template <int SPLIT>
__global__ __launch_bounds__(256, 2) void flash_attn(const bf16* __restrict__ Q,
                                                     const bf16* __restrict__ K,
                                                     const bf16* __restrict__ Vt,
                                                     bf16* __restrict__ Ctx,
                                                     float* __restrict__ P0,
                                                     float* __restrict__ P1,
                                                     float* __restrict__ ML0,
                                                     float* __restrict__ ML1, int L) {
    constexpr int H = 8, HD = 256;
    extern __shared__ __align__(16) bf16 smem[];
    bf16* Ks = smem;                    // [64][256] swizzled
    bf16* Vs = Ks + 64 * 256;           // [256][64] swizzled
    bf16* Ps = Vs + 256 * 64;           // 4 waves x [16][64] swizzled

    const int z = blockIdx.x, h = blockIdx.y;
    const int b    = SPLIT ? ((int)blockIdx.z >> 1) : (int)blockIdx.z;
    const int half = SPLIT ? ((int)blockIdx.z & 1) : 0;
    const int tid = threadIdx.x;
    const int wave = tid >> 6, lane = tid & 63;
    const int quad = lane >> 4, l16 = lane & 15;
    const int nqt = L / 64;

    const bf16* Kb = K + (size_t)b * L * HD;
    const bf16* Vb = Vt + (size_t)b * HD * L;
    bf16* Pw = Ps + wave * 16 * 64;

    // cooperative staging maps; LDS dest linear (elem = tid*8), global source
    // column pre-swizzled (involution; row&7 invariant across rounds).
    const int krow = tid >> 5, kcol = (tid & 31) * 8;
    const int vrow = tid >> 3, vcol = (tid & 7) * 8;
    const int kcs = kcol ^ ((krow & 7) << 3);
    const int vcs = vcol ^ ((vrow & 7) << 3);
    bf16* kdst = Ks + wave * 512;   // + i*2048 per round; wave-uniform
    bf16* vdst = Vs + wave * 512;

    for (int pass = 0; pass < 2; ++pass) {
        const int qt = pass ? z : (nqt - 1 - z);
        const int q0 = qt * 64 + wave * 16;
        const int s  = qt + 1;                    // total KV tiles this q-tile
        const int c0 = (s + 1) >> 1;              // half0 tile count
        const int kt0 = (SPLIT && half) ? c0 : 0;
        const int cnt = SPLIT ? (half ? s - c0 : c0) : s;

        // Q fragments: A-operand layout A[m=l16][k=quad*8+j], k-chunks of 32
        bf16x8 qf[8];
        {
            const bf16* qbase = Q + ((size_t)(b * L + q0 + l16) * H + h) * HD + quad * 8;
#pragma unroll
            for (int kc = 0; kc < 8; ++kc) qf[kc] = *(const bf16x8*)(qbase + kc * 32);
        }

        f32x4 Oacc[16] = {};
        float mrow[4], lrow[4];
#pragma unroll
        for (int r = 0; r < 4; ++r) { mrow[r] = -1e30f; lrow[r] = 0.0f; }

        __syncthreads();  // B0: prev pass's LDS readers done -> reuse safe
        if (cnt > 0) {    // stage tile kt0 (cnt is block-uniform)
            const int kv0 = kt0 * 64;
#pragma unroll
            for (int i = 0; i < 8; ++i)
                gload16(Kb + (size_t)(kv0 + i * 8 + krow) * HD + kcs, kdst + i * 2048);
#pragma unroll
            for (int i = 0; i < 8; ++i)
                gload16(Vb + (size_t)(i * 32 + vrow) * L + kv0 + vcs, vdst + i * 2048);
        }
        __syncthreads();  // B1: vmcnt(0) drained -> tile 0 visible

        for (int it = 0; it < cnt; ++it) {
            const int kt = kt0 + it;
            const int kv0 = kt * 64;
            const int nv0 = kv0 + 64;
            const bool more = (it + 1 < cnt);

            // ---- S = Q K^T from LDS (reads Ks only) ----
            f32x4 S[4];
#pragma unroll
            for (int nt = 0; nt < 4; ++nt) {
                f32x4 slo = {0.f, 0.f, 0.f, 0.f}, shi = {0.f, 0.f, 0.f, 0.f};
                const int krw = nt * 16 + l16;
#pragma unroll
                for (int kc = 0; kc < 4; ++kc)
                    slo = __builtin_amdgcn_mfma_f32_16x16x32_bf16(qf[kc], *(const bf16x8*)&Ks[kswz(krw, quad * 8 + kc * 32)], slo, 0, 0, 0);
#pragma unroll
                for (int kc = 4; kc < 8; ++kc)
                    shi = __builtin_amdgcn_mfma_f32_16x16x32_bf16(qf[kc], *(const bf16x8*)&Ks[kswz(krw, quad * 8 + kc * 32)], shi, 0, 0, 0);
                S[nt] = slo + shi;
            }

            __syncthreads();  // all waves done reading Ks (drains prior V loads, overlapped)
            if (more) {       // stage K(t+1): hidden under softmax+PV below
#pragma unroll
                for (int i = 0; i < 8; ++i)
                    gload16(Kb + (size_t)(nv0 + i * 8 + krow) * HD + kcs, kdst + i * 2048);
            }

            // ---- scale + causal mask (diag tile only) + row max ----
            float rowmax[4] = {-1e30f, -1e30f, -1e30f, -1e30f};
            const bool diag = (kt == qt);
#pragma unroll
            for (int nt = 0; nt < 4; ++nt) {
                const int col = kv0 + nt * 16 + l16;
#pragma unroll
                for (int r = 0; r < 4; ++r) {
                    float sv = S[nt][r] * 0.0625f;  // 1/sqrt(256)
                    if (diag && col > q0 + quad * 4 + r) sv = -1e30f;
                    S[nt][r] = sv;
                    rowmax[r] = fmaxf(rowmax[r], sv);
                }
            }
#pragma unroll
            for (int off = 1; off < 16; off <<= 1)
#pragma unroll
                for (int r = 0; r < 4; ++r)
                    rowmax[r] = fmaxf(rowmax[r], __shfl_xor(rowmax[r], off));

            // ---- online softmax ----
            float alpha[4], rsum[4];
#pragma unroll
            for (int r = 0; r < 4; ++r) {
                const float mnew = fmaxf(mrow[r], rowmax[r]);
                alpha[r] = __expf(mrow[r] - mnew);
                mrow[r] = mnew;
                rsum[r] = 0.0f;
            }
#pragma unroll
            for (int nt = 0; nt < 4; ++nt)
#pragma unroll
                for (int r = 0; r < 4; ++r) {
                    const float p = __expf(S[nt][r] - mrow[r]);
                    rsum[r] += p;
                    Pw[vswz(quad * 4 + r, nt * 16 + l16)] = (bf16)p;  // C-layout
                }
#pragma unroll
            for (int off = 1; off < 16; off <<= 1)
#pragma unroll
                for (int r = 0; r < 4; ++r) rsum[r] += __shfl_xor(rsum[r], off);
#pragma unroll
            for (int r = 0; r < 4; ++r) lrow[r] = lrow[r] * alpha[r] + rsum[r];

            // ---- rescale O, then O += P V from LDS (reads Vs, Pw) ----
#pragma unroll
            for (int nt = 0; nt < 16; ++nt)
#pragma unroll
                for (int r = 0; r < 4; ++r) Oacc[nt][r] *= alpha[r];

            bf16x8 pf[2];
#pragma unroll
            for (int ks = 0; ks < 2; ++ks)
                pf[ks] = *(const bf16x8*)&Pw[vswz(l16, ks * 32 + quad * 8)];
#pragma unroll
            for (int nt = 0; nt < 16; ++nt) {
                const int vrw = nt * 16 + l16;
                f32x4 o = Oacc[nt];
#pragma unroll
                for (int ks = 0; ks < 2; ++ks)
                    o = __builtin_amdgcn_mfma_f32_16x16x32_bf16(pf[ks], *(const bf16x8*)&Vs[vswz(vrw, ks * 32 + quad * 8)], o, 0, 0, 0);
                Oacc[nt] = o;
            }

            __syncthreads();  // Vs/P readers done (drains K(t+1), overlapped)
            if (more) {       // stage V(t+1): hidden under next QK^T
#pragma unroll
                for (int i = 0; i < 8; ++i)
                    gload16(Vb + (size_t)(i * 32 + vrow) * L + nv0 + vcs, vdst + i * 2048);
            }
        }

        if (SPLIT) {
            // ---- epilogue: write un-normalized partial O (f32) + (m,l) ----
            float* Pd  = half ? P1 : P0;
            float* MLd = half ? ML1 : ML0;
            const size_t rowbase = (((size_t)b * H + h) * nqt + qt) * 64 + wave * 16;
            float* prow = Pd + rowbase * 256;
#pragma unroll
            for (int nt = 0; nt < 16; ++nt)
#pragma unroll
                for (int r = 0; r < 4; ++r)
                    prow[(size_t)(quad * 4 + r) * 256 + nt * 16 + l16] = Oacc[nt][r];
            if (l16 == 0) {
#pragma unroll
                for (int r = 0; r < 4; ++r) {
                    const size_t rr = rowbase + quad * 4 + r;
                    MLd[rr * 2 + 0] = mrow[r];
                    MLd[rr * 2 + 1] = lrow[r];
                }
            }
        } else {
            // ---- epilogue: /l, store to Ctx (B,L,H*HD) ----
            bf16* obase = Ctx + ((size_t)(b * L + q0) * H + h) * HD;
#pragma unroll
            for (int nt = 0; nt < 16; ++nt)
#pragma unroll
                for (int r = 0; r < 4; ++r) {
                    const float val = Oacc[nt][r] / lrow[r];
                    obase[(size_t)(quad * 4 + r) * (H * HD) + nt * 16 + l16] = (bf16)val;
                }
        }
    }
}

// ---------------------------------------------------------------------------
// Ctx merge of the two KV halves.
// ---------------------------------------------------------------------------
__global__ __launch_bounds__(256) void merge_partials(const float* __restrict__ P0,
                                                      const float* __restrict__ P1,
                                                      const float* __restrict__ ML0,
                                                      const float* __restrict__ ML1,
                                                      bf16* __restrict__ Ctx, int L) {
    constexpr int H = 8, HD = 256;
    const int qt = blockIdx.x, h = blockIdx.y, b = blockIdx.z;
    const int nqt = L / 64;
    const int t = threadIdx.x;
    const size_t rowbase = (((size_t)b * H + h) * nqt + qt) * 64;
    const int rlo = t >> 6;
    const int d = (t & 63) * 4;
#pragma unroll
    for (int it = 0; it < 16; ++it) {
        const int r = it * 4 + rlo;
        const size_t rr = rowbase + r;
        const float m0 = ML0[rr * 2], l0 = ML0[rr * 2 + 1];
        const float m1 = ML1[rr * 2], l1 = ML1[rr * 2 + 1];
        const float mn = fmaxf(m0, m1);
        const float a0 = __expf(m0 - mn), a1 = __expf(m1 - mn);
        const float linv = 1.0f / (l0 * a0 + l1 * a1);
        const f32x4 o0 = *(const f32x4*)&P0[rr * 256 + d];
        const f32x4 o1 = *(const f32x4*)&P1[rr * 256 + d];
        bf16* op = Ctx + ((size_t)(b * L + qt * 64 + r) * H + h) * HD + d;
#pragma unroll
        for (int j = 0; j < 4; ++j) op[j] = (bf16)((o0[j] * a0 + o1[j] * a1) * linv);
    }
}

// ---------------------------------------------------------------------------
extern "C" void kernel_launch(void* const* d_in, const int* in_sizes, int n_in,
                              void* d_out, int out_size, void* d_ws, size_t ws_size,
                              hipStream_t stream) {
    const float* x      = (const float*)d_in[0];
    const float* q_proj = (const float*)d_in[1];
    const float* k_proj = (const float*)d_in[2];
    const float* v_proj = (const float*)d_in[3];
    const float* o_proj = (const float*)d_in[4];
    const float* q_norm = (const float*)d_in[5];
    const float* k_norm = (const float*)d_in[6];
    float* out = (float*)d_out;

    constexpr int B = 2, L = 2048, D = 2048, H = 8, HD = 256;
    constexpr int M = B * L;            // 4096
    constexpr int NQT = L / 64;         // 32
    constexpr int NQKV = D + 2 * HD;    // 2560
    constexpr int FLASH_LDS = (64 * 256 + 256 * 64 + 4 * 16 * 64) * 2;  // 73,728 B

    static bool attr_set = false;  // host-side once; same device work every call
    if (!attr_set) {
        (void)hipFuncSetAttribute((const void*)flash_attn<0>,
                                  hipFuncAttributeMaxDynamicSharedMemorySize, FLASH_LDS);
        (void)hipFuncSetAttribute((const void*)flash_attn<1>,
                                  hipFuncAttributeMaxDynamicSharedMemorySize, FLASH_LDS);
        attr_set = true;
    }

    bf16* Qw  = (bf16*)d_ws;                 // M * D      (B,L,H,HD)
    bf16* Kw  = Qw  + (size_t)M * D;         // M * HD     (B,L,HD)
    bf16* Vw  = Kw  + (size_t)M * HD;        // M * HD
    bf16* Vtw = Vw  + (size_t)M * HD;        // B * HD * L
    bf16* Ctx = Vtw + (size_t)M * HD;        // M * D

    // Shared region (time-multiplexed, in stream order):
    //   phase 1 (projections): Xb [M*D bf16] + Wqkv [2560*D bf16]
    //   phase 2 (flash):       P0,P1 [f32 partials] + ML0,ML1
    //   phase 3 (o-proj):      Ob [D*D bf16] aliases region start
    char* region = (char*)(Ctx + (size_t)M * D);
    bf16* Xb   = (bf16*)region;
    bf16* Wqkv = Xb + (size_t)M * D;
    constexpr size_t PELEMS  = (size_t)B * H * NQT * 64 * 256;  // 8,388,608
    constexpr size_t MLELEMS = (size_t)B * H * NQT * 64 * 2;    // 65,536
    float* P0  = (float*)region;
    float* P1  = P0 + PELEMS;
    float* ML0 = P1 + PELEMS;
    float* ML1 = ML0 + MLELEMS;
    bf16*  Ob  = (bf16*)region;
    const size_t ws_needed = (size_t)((char*)(ML1 + MLELEMS) - (char*)d_ws);

    if (ws_size >= ws_needed) {
        // ---- fast path ----
        cvt_qkvx<<<2048, 256, 0, stream>>>(x, q_proj, k_proj, v_proj, Xb,
                                           M * D / 8, D * D / 8, HD * D / 8, HD * D / 8);
        gemm_qkv<<<dim3(NQKV / 64, M / 128), 256, 0, stream>>>(Xb, Wqkv, Qw, Kw, Vw, M, D);
        norm_rope2<<<M * H + M, 256, 0, stream>>>(Qw, Kw, q_norm, k_norm, L, M * H);
        transpose_v<<<dim3(L / 32, HD / 32, B), 256, 0, stream>>>(Vw, Vtw, L);
        flash_attn<1><<<dim3(L / 128, H, B * 2), 256, FLASH_LDS, stream>>>(Qw, Kw, Vtw, Ctx,
                                                                           P0, P1, ML0, ML1, L);
        merge_partials<<<dim3(NQT, H, B), 256, 0, stream>>>(P0, P1, ML0, ML1, Ctx, L);
        cvt_bf16<<<2048, 256, 0, stream>>>(o_proj, Ob, D * D / 8);  // Ob aliases dead P0
        gemm_bb<float><<<dim3(D / 64, M / 128), 256, 0, stream>>>(Ctx, Ob, out, M, D, D);
    } else {
        // ---- fallback: fp32-operand GEMMs, single-pass flash ----
        gemm_bt<float, float, bf16><<<dim3(D / 128, M / 128), 256, 0, stream>>>(x, q_proj, Qw, M, D, D);
        gemm_bt<float, float, bf16><<<dim3(HD / 128, M / 128), 256, 0, stream>>>(x, k_proj, Kw, M, HD, D);
        gemm_bt<float, float, bf16><<<dim3(HD / 128, M / 128), 256, 0, stream>>>(x, v_proj, Vw, M, HD, D);
        norm_rope<<<M * H, 256, 0, stream>>>(Qw, q_norm, L, H);
        norm_rope<<<M, 256, 0, stream>>>(Kw, k_norm, L, 1);
        transpose_v<<<dim3(L / 32, HD / 32, B), 256, 0, stream>>>(Vw, Vtw, L);
        flash_attn<0><<<dim3(L / 128, H, B), 256, FLASH_LDS, stream>>>(Qw, Kw, Vtw, Ctx,
                                                                       P0, P1, ML0, ML1, L);
        gemm_bt<bf16, float, float><<<dim3(D / 128, M / 128), 256, 0, stream>>>(Ctx, o_proj, out, M, D, D);
    }
}

// Round 11
// 347.368 us; speedup vs baseline: 1.1031x; 1.0819x over previous
//
#include <hip/hip_runtime.h>
#include <hip/hip_bf16.h>
#include <stdint.h>

typedef __bf16 bf16;
typedef bf16 bf16x8 __attribute__((ext_vector_type(8)));
typedef float f32x4 __attribute__((ext_vector_type(4)));

// Load 8 consecutive elements as a bf16x8 MFMA operand pack.
__device__ __forceinline__ bf16x8 load8(const float* p) {
    const f32x4 lo = *(const f32x4*)p;
    const f32x4 hi = *(const f32x4*)(p + 4);
    bf16x8 v;
#pragma unroll
    for (int r = 0; r < 4; ++r) { v[r] = (bf16)lo[r]; v[4 + r] = (bf16)hi[r]; }
    return v;
}
__device__ __forceinline__ bf16x8 load8(const bf16* p) {
    return *(const bf16x8*)p;
}

// Direct HBM->LDS 16B async copy (no VGPR round trip). LDS dest is
// wave-uniform base + lane*16B; global src is per-lane.
__device__ __forceinline__ void gload16(const bf16* g, bf16* l) {
    __builtin_amdgcn_global_load_lds((const __attribute__((address_space(1))) void*)g,
                                     (__attribute__((address_space(3))) void*)l, 16, 0, 0);
}

// ---------------------------------------------------------------------------
// fp32 -> bf16 bulk convert (RTN (bf16) cast == what load8(float) did inside
// the old GEMM -> numerically identical).
// ---------------------------------------------------------------------------
__global__ __launch_bounds__(256) void cvt_bf16(const float* __restrict__ src,
                                                bf16* __restrict__ dst, int n8) {
    int idx = blockIdx.x * 256 + threadIdx.x;
    const int stride = gridDim.x * 256;
    for (; idx < n8; idx += stride) {
        const f32x4 lo = *(const f32x4*)(src + (size_t)idx * 8);
        const f32x4 hi = *(const f32x4*)(src + (size_t)idx * 8 + 4);
        bf16x8 v;
#pragma unroll
        for (int r = 0; r < 4; ++r) { v[r] = (bf16)lo[r]; v[4 + r] = (bf16)hi[r]; }
        *(bf16x8*)(dst + (size_t)idx * 8) = v;
    }
}

// Fused convert of x, q_proj, k_proj, v_proj into the contiguous Xb|Wqkv
// region (one launch instead of four).
__global__ __launch_bounds__(256) void cvt_qkvx(const float* __restrict__ x,
                                                const float* __restrict__ q,
                                                const float* __restrict__ k,
                                                const float* __restrict__ v,
                                                bf16* __restrict__ dst,
                                                int nx8, int nq8, int nk8, int nv8) {
    const int total = nx8 + nq8 + nk8 + nv8;
    int idx = blockIdx.x * 256 + threadIdx.x;
    const int stride = gridDim.x * 256;
    for (; idx < total; idx += stride) {
        const float* s;
        int off;
        if (idx < nx8)                   { s = x; off = idx; }
        else if (idx < nx8 + nq8)        { s = q; off = idx - nx8; }
        else if (idx < nx8 + nq8 + nk8)  { s = k; off = idx - nx8 - nq8; }
        else                             { s = v; off = idx - nx8 - nq8 - nk8; }
        const f32x4 lo = *(const f32x4*)(s + (size_t)off * 8);
        const f32x4 hi = *(const f32x4*)(s + (size_t)off * 8 + 4);
        bf16x8 o;
#pragma unroll
        for (int r = 0; r < 4; ++r) { o[r] = (bf16)lo[r]; o[4 + r] = (bf16)hi[r]; }
        *(bf16x8*)(dst + (size_t)idx * 8) = o;
    }
}

// ---------------------------------------------------------------------------
// OLD fp32-operand GEMM (small-workspace fallback path only).
// ---------------------------------------------------------------------------
template <typename AT, typename BT, typename CT>
__global__ __launch_bounds__(256) void gemm_bt(const AT* __restrict__ A,
                                               const BT* __restrict__ B,
                                               CT* __restrict__ C,
                                               int M, int N, int K) {
    __shared__ __align__(16) bf16 As[128 * 32];
    __shared__ __align__(16) bf16 Bs[128 * 32];
    const int tid  = threadIdx.x;
    const int wave = tid >> 6, lane = tid & 63;
    const int quad = lane >> 4, l16 = lane & 15;
    const int m0 = blockIdx.y * 128, n0 = blockIdx.x * 128;
    const int wr = (wave >> 1) * 64, wc = (wave & 1) * 64;

    const int srow = wave * 32 + (lane >> 2);
    const int scol = (lane & 3) * 8;
    const AT* Ag = A + (size_t)(m0 + srow) * K + scol;
    const BT* Bg = B + (size_t)(n0 + srow) * K + scol;
    bf16* Asw = &As[srow * 32 + scol];
    bf16* Bsw = &Bs[srow * 32 + scol];

    f32x4 acc[4][4] = {};

    for (int k0 = 0; k0 < K; k0 += 32) {
        const bf16x8 av0 = load8(Ag + k0);
        const bf16x8 av1 = load8(Ag + k0 + (size_t)16 * K);
        const bf16x8 bv0 = load8(Bg + k0);
        const bf16x8 bv1 = load8(Bg + k0 + (size_t)16 * K);
        __syncthreads();
        *(bf16x8*)(Asw)           = av0;
        *(bf16x8*)(Asw + 16 * 32) = av1;
        *(bf16x8*)(Bsw)           = bv0;
        *(bf16x8*)(Bsw + 16 * 32) = bv1;
        __syncthreads();

        bf16x8 a[4], b[4];
#pragma unroll
        for (int i = 0; i < 4; ++i)
            a[i] = *(const bf16x8*)&As[(wr + i * 16 + l16) * 32 + quad * 8];
#pragma unroll
        for (int j = 0; j < 4; ++j)
            b[j] = *(const bf16x8*)&Bs[(wc + j * 16 + l16) * 32 + quad * 8];
#pragma unroll
        for (int i = 0; i < 4; ++i)
#pragma unroll
            for (int j = 0; j < 4; ++j)
                acc[i][j] = __builtin_amdgcn_mfma_f32_16x16x32_bf16(a[i], b[j], acc[i][j], 0, 0, 0);
    }

#pragma unroll
    for (int i = 0; i < 4; ++i)
#pragma unroll
        for (int j = 0; j < 4; ++j) {
            const int row = m0 + wr + i * 16 + quad * 4;
            const int col = n0 + wc + j * 16 + l16;
#pragma unroll
            for (int r = 0; r < 4; ++r)
                C[(size_t)(row + r) * N + col] = (CT)acc[i][j][r];
        }
}

// ---------------------------------------------------------------------------
// bf16 x bf16 GEMM, 128x128 tile, gload staging (REVERTED from 128x64:
// the narrow tile doubled A re-fetch (FETCH 30->71 MB), worsened the
// MFMA:barrier ratio (8 vs 16 MFMA/step) and regressed 62->95us. Matches
// the measured tile-space table: 64-wide = 343 TF vs 128^2 = 912 TF at the
// 2-barrier structure). + XCD-aware block swizzle (T1): contiguous logical
// tiles (sharing A-panels) land on one XCD's L2; grid % 8 == 0 guaranteed.
// C[M,N] = A[M,K] @ B[N,K]^T.
// ---------------------------------------------------------------------------
template <typename CT>
__global__ __launch_bounds__(256) void gemm_bb(const bf16* __restrict__ A,
                                               const bf16* __restrict__ B,
                                               CT* __restrict__ C,
                                               int M, int N, int K) {
    __shared__ __align__(16) bf16 As[128 * 32];
    __shared__ __align__(16) bf16 Bs[128 * 32];
    const int tid  = threadIdx.x;
    const int wave = tid >> 6, lane = tid & 63;
    const int quad = lane >> 4, l16 = lane & 15;
    // XCD swizzle: hw block i runs on XCD i%8; give each XCD a contiguous
    // range of logical tiles.
    const int nx = gridDim.x;
    const int flat = blockIdx.y * nx + blockIdx.x;
    const int cpx = (nx * gridDim.y) >> 3;
    const int swz = (flat & 7) * cpx + (flat >> 3);
    const int m0 = (swz / nx) * 128, n0 = (swz % nx) * 128;
    const int wr = (wave >> 1) * 64, wc = (wave & 1) * 64;

    const int srow = tid >> 2, scol = (tid & 3) * 8;
    const bf16* Ag = A + (size_t)(m0 + srow) * K + scol;
    const bf16* Bg = B + (size_t)(n0 + srow) * K + scol;
    bf16* Adst = As + wave * 512;   // wave-uniform; HW adds lane*16B
    bf16* Bdst = Bs + wave * 512;

    f32x4 acc[4][4] = {};

    for (int k0 = 0; k0 < K; k0 += 32) {
        __syncthreads();  // readers done with LDS
        gload16(Ag + k0, Adst);
        gload16(Ag + k0 + (size_t)64 * K, Adst + 2048);
        gload16(Bg + k0, Bdst);
        gload16(Bg + k0 + (size_t)64 * K, Bdst + 2048);
        __syncthreads();  // vmcnt(0) drained -> tile visible

        bf16x8 a[4], b[4];
#pragma unroll
        for (int i = 0; i < 4; ++i)
            a[i] = *(const bf16x8*)&As[(wr + i * 16 + l16) * 32 + quad * 8];
#pragma unroll
        for (int j = 0; j < 4; ++j)
            b[j] = *(const bf16x8*)&Bs[(wc + j * 16 + l16) * 32 + quad * 8];
#pragma unroll
        for (int i = 0; i < 4; ++i)
#pragma unroll
            for (int j = 0; j < 4; ++j)
                acc[i][j] = __builtin_amdgcn_mfma_f32_16x16x32_bf16(a[i], b[j], acc[i][j], 0, 0, 0);
    }

#pragma unroll
    for (int i = 0; i < 4; ++i)
#pragma unroll
        for (int j = 0; j < 4; ++j) {
            const int row = m0 + wr + i * 16 + quad * 4;
            const int col = n0 + wc + j * 16 + l16;
#pragma unroll
            for (int r = 0; r < 4; ++r)
                C[(size_t)(row + r) * N + col] = (CT)acc[i][j][r];
        }
}

// ---------------------------------------------------------------------------
// Fused QKV projection, 128x128 tile + XCD swizzle: A=Xb [M,2048],
// W=Wqkv [2560,2048] bf16. Epilogue routes per-block (n0 block-uniform):
// [0,2048)->Q, [2048,2304)->K, rest->V.
// ---------------------------------------------------------------------------
__global__ __launch_bounds__(256) void gemm_qkv(const bf16* __restrict__ A,
                                                const bf16* __restrict__ W,
                                                bf16* __restrict__ Cq,
                                                bf16* __restrict__ Ck,
                                                bf16* __restrict__ Cv,
                                                int M, int K) {
    __shared__ __align__(16) bf16 As[128 * 32];
    __shared__ __align__(16) bf16 Bs[128 * 32];
    const int tid  = threadIdx.x;
    const int wave = tid >> 6, lane = tid & 63;
    const int quad = lane >> 4, l16 = lane & 15;
    const int nx = gridDim.x;
    const int flat = blockIdx.y * nx + blockIdx.x;
    const int cpx = (nx * gridDim.y) >> 3;
    const int swz = (flat & 7) * cpx + (flat >> 3);
    const int m0 = (swz / nx) * 128, n0 = (swz % nx) * 128;
    const int wr = (wave >> 1) * 64, wc = (wave & 1) * 64;

    const int srow = tid >> 2, scol = (tid & 3) * 8;
    const bf16* Ag = A + (size_t)(m0 + srow) * K + scol;
    const bf16* Bg = W + (size_t)(n0 + srow) * K + scol;
    bf16* Adst = As + wave * 512;
    bf16* Bdst = Bs + wave * 512;

    f32x4 acc[4][4] = {};

    for (int k0 = 0; k0 < K; k0 += 32) {
        __syncthreads();
        gload16(Ag + k0, Adst);
        gload16(Ag + k0 + (size_t)64 * K, Adst + 2048);
        gload16(Bg + k0, Bdst);
        gload16(Bg + k0 + (size_t)64 * K, Bdst + 2048);
        __syncthreads();

        bf16x8 a[4], b[4];
#pragma unroll
        for (int i = 0; i < 4; ++i)
            a[i] = *(const bf16x8*)&As[(wr + i * 16 + l16) * 32 + quad * 8];
#pragma unroll
        for (int j = 0; j < 4; ++j)
            b[j] = *(const bf16x8*)&Bs[(wc + j * 16 + l16) * 32 + quad * 8];
#pragma unroll
        for (int i = 0; i < 4; ++i)
#pragma unroll
            for (int j = 0; j < 4; ++j)
                acc[i][j] = __builtin_amdgcn_mfma_f32_16x16x32_bf16(a[i], b[j], acc[i][j], 0, 0, 0);
    }

    bf16* cb; int cw, coff;
    if (n0 < 2048)      { cb = Cq; cw = 2048; coff = 0; }
    else if (n0 < 2304) { cb = Ck; cw = 256;  coff = 2048; }
    else                { cb = Cv; cw = 256;  coff = 2304; }

#pragma unroll
    for (int i = 0; i < 4; ++i)
#pragma unroll
        for (int j = 0; j < 4; ++j) {
            const int row = m0 + wr + i * 16 + quad * 4;
            const int col = n0 + wc + j * 16 + l16 - coff;
#pragma unroll
            for (int r = 0; r < 4; ++r)
                cb[(size_t)(row + r) * cw + col] = (bf16)acc[i][j][r];
        }
}

// ---------------------------------------------------------------------------
// RoPE cos/sin table: ct[(pos*128+i)*2] = cos, +1 = sin. Computed once on
// device (~1-2us); replaces ~9.4M per-thread sincos+exp2f in norm_rope
// (trig-heavy op -> table per Appendix B). Identical formula -> identical
// numerics.
// ---------------------------------------------------------------------------
__global__ __launch_bounds__(256) void rope_table(float* __restrict__ ct) {
    const int idx = blockIdx.x * 256 + threadIdx.x;   // pos*128 + i
    const int pos = idx >> 7, i = idx & 127;
    const float freq = (float)pos * exp2f(-(float)i * (19.93156857f / 128.0f));
    ct[idx * 2 + 0] = cosf(freq);
    ct[idx * 2 + 1] = sinf(freq);
}

// ---------------------------------------------------------------------------
// RMSNorm + RoPE (theta=1e6, half=128), in place on bf16; fp32 weights.
// Table version (fast path) + trig version (fallback).
// ---------------------------------------------------------------------------
__device__ __forceinline__ void norm_rope_core(bf16* __restrict__ x,
                                               const float* __restrict__ w,
                                               int rid, int t,
                                               float c, float s) {
    const size_t base = (size_t)rid * 256;
    const float v = (float)x[base + t];
    float ss = v * v;
#pragma unroll
    for (int off = 32; off >= 1; off >>= 1) ss += __shfl_xor(ss, off);

    __shared__ float wsum[4];
    __shared__ float buf[256];
    const int wave = t >> 6, lane = t & 63;
    if (lane == 0) wsum[wave] = ss;
    __syncthreads();
    const float var = (wsum[0] + wsum[1] + wsum[2] + wsum[3]) * (1.0f / 256.0f);
    const float inv = rsqrtf(var + 1e-6f);
    buf[t] = v * inv * w[t];
    __syncthreads();

    const int i = t & 127;
    const float x1 = buf[i], x2 = buf[i + 128];
    const float out = (t < 128) ? (x1 * c - x2 * s) : (x1 * s + x2 * c);
    x[base + t] = (bf16)out;
}

__global__ __launch_bounds__(256) void norm_rope(bf16* __restrict__ x,
                                                 const float* __restrict__ w,
                                                 int L, int div) {
    const int rid = blockIdx.x, t = threadIdx.x;
    const int pos = (rid / div) % L;
    const int i = t & 127;
    const float freq = (float)pos * exp2f(-(float)i * (19.93156857f / 128.0f));
    norm_rope_core(x, w, rid, t, cosf(freq), sinf(freq));
}

__global__ __launch_bounds__(256) void norm_rope2(bf16* __restrict__ Q,
                                                  bf16* __restrict__ K,
                                                  const float* __restrict__ qw,
                                                  const float* __restrict__ kw,
                                                  const float* __restrict__ ct,
                                                  int L, int MH) {
    const int row = blockIdx.x, t = threadIdx.x;
    bf16* x; const float* w; int rid, pos;
    if (row < MH) { x = Q; w = qw; rid = row;      pos = (rid >> 3) & (L - 1); }
    else          { x = K; w = kw; rid = row - MH; pos = rid & (L - 1); }
    const int i = t & 127;
    const float c = ct[(pos * 128 + i) * 2 + 0];
    const float s = ct[(pos * 128 + i) * 2 + 1];
    norm_rope_core(x, w, rid, t, c, s);
}

// ---------------------------------------------------------------------------
// Vt[b][d][l] = V[b][l][d]
// ---------------------------------------------------------------------------
__global__ __launch_bounds__(256) void transpose_v(const bf16* __restrict__ V,
                                                   bf16* __restrict__ Vt, int L) {
    __shared__ bf16 tile[32][33];
    const int b = blockIdx.z;
    const int l0 = blockIdx.x * 32, d0 = blockIdx.y * 32;
    const int tx = threadIdx.x & 31, ty = threadIdx.x >> 5;
#pragma unroll
    for (int i = 0; i < 32; i += 8)
        tile[ty + i][tx] = V[((size_t)b * L + l0 + ty + i) * 256 + d0 + tx];
    __syncthreads();
#pragma unroll
    for (int i = 0; i < 32; i += 8)
        Vt[((size_t)b * 256 + d0 + ty + i) * L + l0 + tx] = tile[tx][ty + i];
}

// XOR-swizzled LDS element indices (col ^= (row&7)<<3 for bf16; 16B granular).
__device__ __forceinline__ int kswz(int r, int c) { return r * 256 + (c ^ ((r & 7) << 3)); }
__device__ __forceinline__ int vswz(int r, int c) { return r * 64  + (c ^ ((r & 7) << 3)); }

// ---------------------------------------------------------------------------
// Causal MQA flash attention, v9 + setprio (T5: +4-7% on attn with
// co-resident independent blocks — exactly our 2-blocks/CU structure).
// Block (z,half) does half the KV range of q-tile pair {nqt-1-z, z}.
// SPLIT=1 writes f32 partials + (m,l); merge_partials combines.
// ---------------------------------------------------------------------------
template <int SPLIT>
__global__ __launch_bounds__(256, 2) void flash_attn(const bf16* __restrict__ Q,
                                                     const bf16* __restrict__ K,
                                                     const bf16* __restrict__ Vt,
                                                     bf16* __restrict__ Ctx,
                                                     float* __restrict__ P0,
                                                     float* __restrict__ P1,
                                                     float* __restrict__ ML0,
                                                     float* __restrict__ ML1, int L) {
    constexpr int H = 8, HD = 256;
    extern __shared__ __align__(16) bf16 smem[];
    bf16* Ks = smem;                    // [64][256] swizzled
    bf16* Vs = Ks + 64 * 256;           // [256][64] swizzled
    bf16* Ps = Vs + 256 * 64;           // 4 waves x [16][64] swizzled

    const int z = blockIdx.x, h = blockIdx.y;
    const int b    = SPLIT ? ((int)blockIdx.z >> 1) : (int)blockIdx.z;
    const int half = SPLIT ? ((int)blockIdx.z & 1) : 0;
    const int tid = threadIdx.x;
    const int wave = tid >> 6, lane = tid & 63;
    const int quad = lane >> 4, l16 = lane & 15;
    const int nqt = L / 64;

    const bf16* Kb = K + (size_t)b * L * HD;
    const bf16* Vb = Vt + (size_t)b * HD * L;
    bf16* Pw = Ps + wave * 16 * 64;

    // cooperative staging maps; LDS dest linear (elem = tid*8), global source
    // column pre-swizzled (involution; row&7 invariant across rounds).
    const int krow = tid >> 5, kcol = (tid & 31) * 8;
    const int vrow = tid >> 3, vcol = (tid & 7) * 8;
    const int kcs = kcol ^ ((krow & 7) << 3);
    const int vcs = vcol ^ ((vrow & 7) << 3);
    bf16* kdst = Ks + wave * 512;   // + i*2048 per round; wave-uniform
    bf16* vdst = Vs + wave * 512;

    for (int pass = 0; pass < 2; ++pass) {
        const int qt = pass ? z : (nqt - 1 - z);
        const int q0 = qt * 64 + wave * 16;
        const int s  = qt + 1;                    // total KV tiles this q-tile
        const int c0 = (s + 1) >> 1;              // half0 tile count
        const int kt0 = (SPLIT && half) ? c0 : 0;
        const int cnt = SPLIT ? (half ? s - c0 : c0) : s;

        // Q fragments: A-operand layout A[m=l16][k=quad*8+j], k-chunks of 32
        bf16x8 qf[8];
        {
            const bf16* qbase = Q + ((size_t)(b * L + q0 + l16) * H + h) * HD + quad * 8;
#pragma unroll
            for (int kc = 0; kc < 8; ++kc) qf[kc] = *(const bf16x8*)(qbase + kc * 32);
        }

        f32x4 Oacc[16] = {};
        float mrow[4], lrow[4];
#pragma unroll
        for (int r = 0; r < 4; ++r) { mrow[r] = -1e30f; lrow[r] = 0.0f; }

        __syncthreads();  // B0: prev pass's LDS readers done -> reuse safe
        if (cnt > 0) {    // stage tile kt0 (cnt is block-uniform)
            const int kv0 = kt0 * 64;
#pragma unroll
            for (int i = 0; i < 8; ++i)
                gload16(Kb + (size_t)(kv0 + i * 8 + krow) * HD + kcs, kdst + i * 2048);
#pragma unroll
            for (int i = 0; i < 8; ++i)
                gload16(Vb + (size_t)(i * 32 + vrow) * L + kv0 + vcs, vdst + i * 2048);
        }
        __syncthreads();  // B1: vmcnt(0) drained -> tile 0 visible

        for (int it = 0; it < cnt; ++it) {
            const int kt = kt0 + it;
            const int kv0 = kt * 64;
            const int nv0 = kv0 + 64;
            const bool more = (it + 1 < cnt);

            // ---- S = Q K^T from LDS (reads Ks only) ----
            f32x4 S[4];
            __builtin_amdgcn_s_setprio(1);
#pragma unroll
            for (int nt = 0; nt < 4; ++nt) {
                f32x4 slo = {0.f, 0.f, 0.f, 0.f}, shi = {0.f, 0.f, 0.f, 0.f};
                const int krw = nt * 16 + l16;
#pragma unroll
                for (int kc = 0; kc < 4; ++kc)
                    slo = __builtin_amdgcn_mfma_f32_16x16x32_bf16(qf[kc], *(const bf16x8*)&Ks[kswz(krw, quad * 8 + kc * 32)], slo, 0, 0, 0);
#pragma unroll
                for (int kc = 4; kc < 8; ++kc)
                    shi = __builtin_amdgcn_mfma_f32_16x16x32_bf16(qf[kc], *(const bf16x8*)&Ks[kswz(krw, quad * 8 + kc * 32)], shi, 0, 0, 0);
                S[nt] = slo + shi;
            }
            __builtin_amdgcn_s_setprio(0);

            __syncthreads();  // all waves done reading Ks (drains prior V loads, overlapped)
            if (more) {       // stage K(t+1): hidden under softmax+PV below
#pragma unroll
                for (int i = 0; i < 8; ++i)
                    gload16(Kb + (size_t)(nv0 + i * 8 + krow) * HD + kcs, kdst + i * 2048);
            }

            // ---- scale + causal mask (diag tile only) + row max ----
            float rowmax[4] = {-1e30f, -1e30f, -1e30f, -1e30f};
            const bool diag = (kt == qt);
#pragma unroll
            for (int nt = 0; nt < 4; ++nt) {
                const int col = kv0 + nt * 16 + l16;
#pragma unroll
                for (int r = 0; r < 4; ++r) {
                    float sv = S[nt][r] * 0.0625f;  // 1/sqrt(256)
                    if (diag && col > q0 + quad * 4 + r) sv = -1e30f;
                    S[nt][r] = sv;
                    rowmax[r] = fmaxf(rowmax[r], sv);
                }
            }
#pragma unroll
            for (int off = 1; off < 16; off <<= 1)
#pragma unroll
                for (int r = 0; r < 4; ++r)
                    rowmax[r] = fmaxf(rowmax[r], __shfl_xor(rowmax[r], off));

            // ---- online softmax ----
            float alpha[4], rsum[4];
#pragma unroll
            for (int r = 0; r < 4; ++r) {
                const float mnew = fmaxf(mrow[r], rowmax[r]);
                alpha[r] = __expf(mrow[r] - mnew);
                mrow[r] = mnew;
                rsum[r] = 0.0f;
            }
#pragma unroll
            for (int nt = 0; nt < 4; ++nt)
#pragma unroll
                for (int r = 0; r < 4; ++r) {
                    const float p = __expf(S[nt][r] - mrow[r]);
                    rsum[r] += p;
                    Pw[vswz(quad * 4 + r, nt * 16 + l16)] = (bf16)p;  // C-layout
                }
#pragma unroll
            for (int off = 1; off < 16; off <<= 1)
#pragma unroll
                for (int r = 0; r < 4; ++r) rsum[r] += __shfl_xor(rsum[r], off);
#pragma unroll
            for (int r = 0; r < 4; ++r) lrow[r] = lrow[r] * alpha[r] + rsum[r];

            // ---- rescale O, then O += P V from LDS (reads Vs, Pw) ----
#pragma unroll
            for (int nt = 0; nt < 16; ++nt)
#pragma unroll
                for (int r = 0; r < 4; ++r) Oacc[nt][r] *= alpha[r];

            bf16x8 pf[2];
#pragma unroll
            for (int ks = 0; ks < 2; ++ks)
                pf[ks] = *(const bf16x8*)&Pw[vswz(l16, ks * 32 + quad * 8)];
            __builtin_amdgcn_s_setprio(1);
#pragma unroll
            for (int nt = 0; nt < 16; ++nt) {
                const int vrw = nt * 16 + l16;
                f32x4 o = Oacc[nt];
#pragma unroll
                for (int ks = 0; ks < 2; ++ks)
                    o = __builtin_amdgcn_mfma_f32_16x16x32_bf16(pf[ks], *(const bf16x8*)&Vs[vswz(vrw, ks * 32 + quad * 8)], o, 0, 0, 0);
                Oacc[nt] = o;
            }
            __builtin_amdgcn_s_setprio(0);

            __syncthreads();  // Vs/P readers done (drains K(t+1), overlapped)
            if (more) {       // stage V(t+1): hidden under next QK^T
#pragma unroll
                for (int i = 0; i < 8; ++i)
                    gload16(Vb + (size_t)(i * 32 + vrow) * L + nv0 + vcs, vdst + i * 2048);
            }
        }

        if (SPLIT) {
            // ---- epilogue: write un-normalized partial O (f32) + (m,l) ----
            float* Pd  = half ? P1 : P0;
            float* MLd = half ? ML1 : ML0;
            const size_t rowbase = (((size_t)b * H + h) * nqt + qt) * 64 + wave * 16;
            float* prow = Pd + rowbase * 256;
#pragma unroll
            for (int nt = 0; nt < 16; ++nt)
#pragma unroll
                for (int r = 0; r < 4; ++r)
                    prow[(size_t)(quad * 4 + r) * 256 + nt * 16 + l16] = Oacc[nt][r];
            if (l16 == 0) {
#pragma unroll
                for (int r = 0; r < 4; ++r) {
                    const size_t rr = rowbase + quad * 4 + r;
                    MLd[rr * 2 + 0] = mrow[r];
                    MLd[rr * 2 + 1] = lrow[r];
                }
            }
        } else {
            // ---- epilogue: /l, store to Ctx (B,L,H*HD) ----
            bf16* obase = Ctx + ((size_t)(b * L + q0) * H + h) * HD;
#pragma unroll
            for (int nt = 0; nt < 16; ++nt)
#pragma unroll
                for (int r = 0; r < 4; ++r) {
                    const float val = Oacc[nt][r] / lrow[r];
                    obase[(size_t)(quad * 4 + r) * (H * HD) + nt * 16 + l16] = (bf16)val;
                }
        }
    }
}

// ---------------------------------------------------------------------------
// Ctx merge of the two KV halves.
// ---------------------------------------------------------------------------
__global__ __launch_bounds__(256) void merge_partials(const float* __restrict__ P0,
                                                      const float* __restrict__ P1,
                                                      const float* __restrict__ ML0,
                                                      const float* __restrict__ ML1,
                                                      bf16* __restrict__ Ctx, int L) {
    constexpr int H = 8, HD = 256;
    const int qt = blockIdx.x, h = blockIdx.y, b = blockIdx.z;
    const int nqt = L / 64;
    const int t = threadIdx.x;
    const size_t rowbase = (((size_t)b * H + h) * nqt + qt) * 64;
    const int rlo = t >> 6;
    const int d = (t & 63) * 4;
#pragma unroll
    for (int it = 0; it < 16; ++it) {
        const int r = it * 4 + rlo;
        const size_t rr = rowbase + r;
        const float m0 = ML0[rr * 2], l0 = ML0[rr * 2 + 1];
        const float m1 = ML1[rr * 2], l1 = ML1[rr * 2 + 1];
        const float mn = fmaxf(m0, m1);
        const float a0 = __expf(m0 - mn), a1 = __expf(m1 - mn);
        const float linv = 1.0f / (l0 * a0 + l1 * a1);
        const f32x4 o0 = *(const f32x4*)&P0[rr * 256 + d];
        const f32x4 o1 = *(const f32x4*)&P1[rr * 256 + d];
        bf16* op = Ctx + ((size_t)(b * L + qt * 64 + r) * H + h) * HD + d;
#pragma unroll
        for (int j = 0; j < 4; ++j) op[j] = (bf16)((o0[j] * a0 + o1[j] * a1) * linv);
    }
}

// ---------------------------------------------------------------------------
extern "C" void kernel_launch(void* const* d_in, const int* in_sizes, int n_in,
                              void* d_out, int out_size, void* d_ws, size_t ws_size,
                              hipStream_t stream) {
    const float* x      = (const float*)d_in[0];
    const float* q_proj = (const float*)d_in[1];
    const float* k_proj = (const float*)d_in[2];
    const float* v_proj = (const float*)d_in[3];
    const float* o_proj = (const float*)d_in[4];
    const float* q_norm = (const float*)d_in[5];
    const float* k_norm = (const float*)d_in[6];
    float* out = (float*)d_out;

    constexpr int B = 2, L = 2048, D = 2048, H = 8, HD = 256;
    constexpr int M = B * L;            // 4096
    constexpr int NQT = L / 64;         // 32
    constexpr int NQKV = D + 2 * HD;    // 2560
    constexpr int FLASH_LDS = (64 * 256 + 256 * 64 + 4 * 16 * 64) * 2;  // 73,728 B

    static bool attr_set = false;  // host-side once; same device work every call
    if (!attr_set) {
        (void)hipFuncSetAttribute((const void*)flash_attn<0>,
                                  hipFuncAttributeMaxDynamicSharedMemorySize, FLASH_LDS);
        (void)hipFuncSetAttribute((const void*)flash_attn<1>,
                                  hipFuncAttributeMaxDynamicSharedMemorySize, FLASH_LDS);
        attr_set = true;
    }

    bf16* Qw  = (bf16*)d_ws;                 // M * D      (B,L,H,HD)
    bf16* Kw  = Qw  + (size_t)M * D;         // M * HD     (B,L,HD)
    bf16* Vw  = Kw  + (size_t)M * HD;        // M * HD
    bf16* Vtw = Vw  + (size_t)M * HD;        // B * HD * L
    bf16* Ctx = Vtw + (size_t)M * HD;        // M * D

    // Shared region (time-multiplexed, in stream order):
    //   phase 1 (projections): Xb [M*D bf16] + Wqkv [2560*D bf16]
    //   phase 1b (norm_rope):  RT rope table [L*128*2 f32] aliases dead Xb
    //   phase 2 (flash):       P0,P1 [f32 partials] + ML0,ML1
    //   phase 3 (o-proj):      Ob [D*D bf16] aliases region start
    char* region = (char*)(Ctx + (size_t)M * D);
    bf16* Xb   = (bf16*)region;
    bf16* Wqkv = Xb + (size_t)M * D;
    float* RT  = (float*)region;                         // 2 MB
    constexpr size_t PELEMS  = (size_t)B * H * NQT * 64 * 256;  // 8,388,608
    constexpr size_t MLELEMS = (size_t)B * H * NQT * 64 * 2;    // 65,536
    float* P0  = (float*)region;
    float* P1  = P0 + PELEMS;
    float* ML0 = P1 + PELEMS;
    float* ML1 = ML0 + MLELEMS;
    bf16*  Ob  = (bf16*)region;
    const size_t ws_needed = (size_t)((char*)(ML1 + MLELEMS) - (char*)d_ws);

    if (ws_size >= ws_needed) {
        // ---- fast path ----
        cvt_qkvx<<<2048, 256, 0, stream>>>(x, q_proj, k_proj, v_proj, Xb,
                                           M * D / 8, D * D / 8, HD * D / 8, HD * D / 8);
        gemm_qkv<<<dim3(NQKV / 128, M / 128), 256, 0, stream>>>(Xb, Wqkv, Qw, Kw, Vw, M, D);
        rope_table<<<L * 128 / 256, 256, 0, stream>>>(RT);  // aliases dead Xb
        norm_rope2<<<M * H + M, 256, 0, stream>>>(Qw, Kw, q_norm, k_norm, RT, L, M * H);
        transpose_v<<<dim3(L / 32, HD / 32, B), 256, 0, stream>>>(Vw, Vtw, L);
        flash_attn<1><<<dim3(L / 128, H, B * 2), 256, FLASH_LDS, stream>>>(Qw, Kw, Vtw, Ctx,
                                                                           P0, P1, ML0, ML1, L);
        merge_partials<<<dim3(NQT, H, B), 256, 0, stream>>>(P0, P1, ML0, ML1, Ctx, L);
        cvt_bf16<<<2048, 256, 0, stream>>>(o_proj, Ob, D * D / 8);  // Ob aliases dead P0
        gemm_bb<float><<<dim3(D / 128, M / 128), 256, 0, stream>>>(Ctx, Ob, out, M, D, D);
    } else {
        // ---- fallback: fp32-operand GEMMs, single-pass flash ----
        gemm_bt<float, float, bf16><<<dim3(D / 128, M / 128), 256, 0, stream>>>(x, q_proj, Qw, M, D, D);
        gemm_bt<float, float, bf16><<<dim3(HD / 128, M / 128), 256, 0, stream>>>(x, k_proj, Kw, M, HD, D);
        gemm_bt<float, float, bf16><<<dim3(HD / 128, M / 128), 256, 0, stream>>>(x, v_proj, Vw, M, HD, D);
        norm_rope<<<M * H, 256, 0, stream>>>(Qw, q_norm, L, H);
        norm_rope<<<M, 256, 0, stream>>>(Kw, k_norm, L, 1);
        transpose_v<<<dim3(L / 32, HD / 32, B), 256, 0, stream>>>(Vw, Vtw, L);
        flash_attn<0><<<dim3(L / 128, H, B), 256, FLASH_LDS, stream>>>(Qw, Kw, Vtw, Ctx,
                                                                       P0, P1, ML0, ML1, L);
        gemm_bt<bf16, float, float><<<dim3(D / 128, M / 128), 256, 0, stream>>>(Ctx, o_proj, out, M, D, D);
    }
}